// Round 4
// baseline (13493.887 us; speedup 1.0000x reference)
//
#include <hip/hip_runtime.h>
#include <math.h>

// ---------------- problem constants ----------------
static const int N_NODES = 50000;
static const int N_EDGES = 800000;
static const int F_IN    = 500;
static const int C_DIM   = 128;

__device__ __forceinline__ float sigmoidf_(float x) { return 1.f / (1.f + __expf(-x)); }

// ---------------- ortho-norm (per-layer 128x128 cholesky + solve) ----------------
// Writes WoT[li][j*128+k] = Wo[k][j]  (so downstream GEMM does out[n][j]=sum_k A[n][k]*B[j][k])
__global__ __launch_bounds__(256) void ortho_kernel(const float* __restrict__ conv_w,
                                                    float* __restrict__ woT)
{
    __shared__ float Wm[128][129];
    __shared__ float Am[128][129];
    const int li  = blockIdx.x;
    const int tid = threadIdx.x;
    const float* W = conv_w + (size_t)li * 16384;

    for (int idx = tid; idx < 16384; idx += 256) {
        int r = idx >> 7, c = idx & 127;
        Wm[r][c] = W[idx];
    }
    __syncthreads();
    // A = W^T W + 1e-4 I
    for (int idx = tid; idx < 16384; idx += 256) {
        int i = idx >> 7, j = idx & 127;
        float s = 0.f;
        for (int k = 0; k < 128; ++k) s += Wm[k][i] * Wm[k][j];
        if (i == j) s += 1e-4f;
        Am[i][j] = s;
    }
    __syncthreads();
    // in-place lower cholesky
    for (int k = 0; k < 128; ++k) {
        if (tid == 0) Am[k][k] = sqrtf(Am[k][k]);
        __syncthreads();
        float dinv = 1.f / Am[k][k];
        for (int i = k + 1 + tid; i < 128; i += 256) Am[i][k] *= dinv;
        __syncthreads();
        for (int idx = tid; idx < 16384; idx += 256) {
            int i = idx >> 7, j = idx & 127;
            if (i > k && j > k && j <= i) Am[i][j] -= Am[i][k] * Am[j][k];
        }
        __syncthreads();
    }
    // forward solve L Y = W^T ; store Y[k][j] into Wm[j][k] (thread j owns row j)
    if (tid < 128) {
        int j = tid;
        for (int k = 0; k < 128; ++k) {
            float v = Wm[j][k];
            for (int m = 0; m < k; ++m) v -= Am[k][m] * Wm[j][m];
            Wm[j][k] = v / Am[k][k];
        }
    }
    __syncthreads();
    // WoT[j*128+k] = Wo[k][j] = Wm[k][j]
    float* o = woT + (size_t)li * 16384;
    for (int idx = tid; idx < 16384; idx += 256) {
        int j = idx >> 7, k = idx & 127;
        o[idx] = Wm[k][j];
    }
}

// ---------------- input FC: h0 = relu(x @ w.T + b), duplicated to two buffers ----------------
__global__ __launch_bounds__(256) void fc_relu_kernel(const float* __restrict__ x,
                                                      const float* __restrict__ w,
                                                      const float* __restrict__ b,
                                                      float* __restrict__ h0,
                                                      float* __restrict__ h1,
                                                      int nrows)
{
    __shared__ float ws[128][101];
    __shared__ float xs[32][101];
    const int tid = threadIdx.x;
    const int n0  = blockIdx.x * 32;
    const int cq  = tid & 31;        // column group base
    const int rh  = tid >> 5;        // 0..7 -> rows rh*4 + rr
    float acc[4][4] = {};

    for (int kc = 0; kc < 500; kc += 100) {
        for (int idx = tid; idx < 12800; idx += 256) {
            int j = idx / 100, k = idx % 100;
            ws[j][k] = w[j * 500 + kc + k];
        }
        for (int idx = tid; idx < 3200; idx += 256) {
            int r = idx / 100, k = idx % 100;
            int n = n0 + r;
            xs[r][k] = (n < nrows) ? x[(size_t)n * 500 + kc + k] : 0.f;
        }
        __syncthreads();
        for (int k = 0; k < 100; ++k) {
            float b0 = ws[cq][k], b1 = ws[cq + 32][k], b2 = ws[cq + 64][k], b3 = ws[cq + 96][k];
#pragma unroll
            for (int rr = 0; rr < 4; ++rr) {
                float a = xs[rh * 4 + rr][k];
                acc[rr][0] += a * b0; acc[rr][1] += a * b1;
                acc[rr][2] += a * b2; acc[rr][3] += a * b3;
            }
        }
        __syncthreads();
    }
#pragma unroll
    for (int rr = 0; rr < 4; ++rr) {
        int n = n0 + rh * 4 + rr;
        if (n >= nrows) continue;
#pragma unroll
        for (int ci = 0; ci < 4; ++ci) {
            int j = cq + 32 * ci;
            float v = fmaxf(acc[rr][ci] + b[j], 0.f);
            h0[(size_t)n * 128 + j] = v;
            h1[(size_t)n * 128 + j] = v;
        }
    }
}

// ---------------- generic 128x128 GEMM: out[n][j] = sum_k A[n][k]*B[j][k]  ----------------
// MODE 0: A = A0, epilogue  out = acc + bias[j]            (attention x2)
// MODE 1: A = c0*A0 + c1*A1 (support), epilogue out = relu(tanh(theta*acc + (1-theta)*support)) [* watt]
template <int MODE>
__global__ __launch_bounds__(256) void gemm128_kernel(const float* __restrict__ A0,
                                                      const float* __restrict__ A1,
                                                      const float* __restrict__ Bw,
                                                      const float* __restrict__ bias,
                                                      const float* __restrict__ watt,
                                                      float* __restrict__ outp,
                                                      float c0, float c1, float theta,
                                                      int nrows)
{
    __shared__ float Bs[128][65];
    __shared__ float As[64][65];
    const int tid = threadIdx.x;
    const int n0  = blockIdx.x * 64;
    const int cq  = tid & 31;     // cols cq + 32*ci
    const int rh  = tid >> 5;     // rows rh*8 + rr
    float acc[8][4] = {};

    for (int kc = 0; kc < 128; kc += 64) {
        for (int idx = tid; idx < 128 * 64; idx += 256) {
            int j = idx >> 6, k = idx & 63;
            Bs[j][k] = Bw[j * 128 + kc + k];
        }
        for (int idx = tid; idx < 64 * 64; idx += 256) {
            int r = idx >> 6, k = idx & 63;
            int n = n0 + r;
            float v = 0.f;
            if (n < nrows) {
                v = c0 * A0[(size_t)n * 128 + kc + k];
                if (MODE == 1) v += c1 * A1[(size_t)n * 128 + kc + k];
            }
            As[r][k] = v;
        }
        __syncthreads();
        for (int k = 0; k < 64; ++k) {
            float b0 = Bs[cq][k], b1 = Bs[cq + 32][k], b2 = Bs[cq + 64][k], b3 = Bs[cq + 96][k];
#pragma unroll
            for (int rr = 0; rr < 8; ++rr) {
                float a = As[rh * 8 + rr][k];
                acc[rr][0] += a * b0; acc[rr][1] += a * b1;
                acc[rr][2] += a * b2; acc[rr][3] += a * b3;
            }
        }
        __syncthreads();
    }
#pragma unroll
    for (int rr = 0; rr < 8; ++rr) {
        int n = n0 + rh * 8 + rr;
        if (n >= nrows) continue;
#pragma unroll
        for (int ci = 0; ci < 4; ++ci) {
            int j = cq + 32 * ci;
            float v = acc[rr][ci];
            if (MODE == 0) {
                v += bias[j];
            } else {
                float s = c0 * A0[(size_t)n * 128 + j] + c1 * A1[(size_t)n * 128 + j];
                v = theta * v + (1.f - theta) * s;
                v = tanhf(v);
                v = fmaxf(v, 0.f);
                if (watt) v *= watt[(size_t)n * 128 + j];
            }
            outp[(size_t)n * 128 + j] = v;
        }
    }
}

// ---------------- attention elementwise (view 0): conv1d/sigmoid gating ----------------
__global__ __launch_bounds__(256) void att_kernel(const float* __restrict__ h,
                                                  const float* __restrict__ x2g,
                                                  const float* __restrict__ cw,
                                                  const float* __restrict__ mwp,
                                                  float* __restrict__ watt,
                                                  float* __restrict__ hout,
                                                  int nrows)
{
    __shared__ float hrow[2][132];
    __shared__ float orow[2][132];
    __shared__ float red[2][2][2];
    const int tid = threadIdx.x;
    const int c   = tid & 127;
    const int rl  = tid >> 7;
    const int n   = blockIdx.x * 2 + rl;
    const bool valid = n < nrows;
    float hv = 0.f, x2v = 0.f;
    if (valid) { hv = h[(size_t)n * 128 + c]; x2v = x2g[(size_t)n * 128 + c]; }
    hrow[rl][c + 2] = hv;
    if (c < 2) { hrow[rl][c] = 0.f; hrow[rl][c + 130] = 0.f; }
    const float w0 = cw[0], w1 = cw[1], w2 = cw[2], w3 = cw[3], w4 = cw[4];
    __syncthreads();
    float x1 = w0 * hrow[rl][c] + w1 * hrow[rl][c + 1] + w2 * hrow[rl][c + 2]
             + w3 * hrow[rl][c + 3] + w4 * hrow[rl][c + 4];
    float p1 = x1, p2 = x2v;
#pragma unroll
    for (int off = 32; off; off >>= 1) { p1 += __shfl_xor(p1, off); p2 += __shfl_xor(p2, off); }
    int wir = (tid >> 6) & 1;
    if ((tid & 63) == 0) { red[rl][0][wir] = p1; red[rl][1][wir] = p2; }
    __syncthreads();
    float s1 = red[rl][0][0] + red[rl][0][1];
    float s2 = red[rl][1][0] + red[rl][1][1];
    float m  = sigmoidf_(mwp[0]);
    float o  = m * sigmoidf_(s1 * x2v) + (1.f - m) * sigmoidf_(s2 * x1);
    orow[rl][c + 2] = o;
    if (c < 2) { orow[rl][c] = 0.f; orow[rl][c + 130] = 0.f; }
    __syncthreads();
    float wv = w0 * orow[rl][c] + w1 * orow[rl][c + 1] + w2 * orow[rl][c + 2]
             + w3 * orow[rl][c + 3] + w4 * orow[rl][c + 4];
    wv = sigmoidf_(wv);
    if (valid) {
        watt[(size_t)n * 128 + c] = wv;
        hout[(size_t)n * 128 + c] = hv * wv;
    }
}

// ---------------- SpMM: hi[r] += v * h[c]  (atomic scatter, 4 channels/thread) ----------------
__global__ __launch_bounds__(256) void spmm_atomic_kernel(const int* __restrict__ rows,
                                                          const int* __restrict__ cols,
                                                          const float* __restrict__ vals,
                                                          const float* __restrict__ h,
                                                          float* __restrict__ hi,
                                                          int nedges)
{
    int gid = blockIdx.x * 256 + threadIdx.x;
    int e = gid >> 5;
    if (e >= nedges) return;
    int c0 = (gid & 31) * 4;
    int r = rows[e], c = cols[e];
    float v = vals[e];
    const float4 hv = *reinterpret_cast<const float4*>(&h[(size_t)c * 128 + c0]);
    float* dst = &hi[(size_t)r * 128 + c0];
    atomicAdd(dst + 0, v * hv.x);
    atomicAdd(dst + 1, v * hv.y);
    atomicAdd(dst + 2, v * hv.z);
    atomicAdd(dst + 3, v * hv.w);
}

// ---------------- final: logits (both views), 4x log-softmax outputs ----------------
__global__ __launch_bounds__(256) void out_kernel(const float* __restrict__ hA,
                                                  const float* __restrict__ hB,
                                                  const float* __restrict__ ow,
                                                  const float* __restrict__ ob,
                                                  float* __restrict__ outp,
                                                  int nrows)
{
    const int tid  = threadIdx.x;
    const int lane = tid & 63;
    const int wid  = tid >> 6;
    const int n    = blockIdx.x * 4 + wid;
    if (n >= nrows) return;
    const int j   = lane & 15;
    const int seg = lane >> 4;
    const float* a  = &hA[(size_t)n * 128 + seg * 32];
    const float* bx = &hB[(size_t)n * 128 + seg * 32];
    const float* wj = &ow[j * 128 + seg * 32];
    float d0 = 0.f, d1 = 0.f;
#pragma unroll
    for (int k = 0; k < 32; ++k) { float wv = wj[k]; d0 += a[k] * wv; d1 += bx[k] * wv; }
    d0 += __shfl_xor(d0, 16); d0 += __shfl_xor(d0, 32);
    d1 += __shfl_xor(d1, 16); d1 += __shfl_xor(d1, 32);
    float bias = ob[j];
    float l0 = d0 + bias, l1 = d1 + bias, lt = l0 + l1;

    float mt = lt, m0 = l0, m1 = l1;
#pragma unroll
    for (int off = 8; off; off >>= 1) {
        mt = fmaxf(mt, __shfl_xor(mt, off));
        m0 = fmaxf(m0, __shfl_xor(m0, off));
        m1 = fmaxf(m1, __shfl_xor(m1, off));
    }
    float et = __expf(lt - mt), e0 = __expf(l0 - m0), e1 = __expf(l1 - m1);
    float st = et, s0 = e0, s1 = e1;
#pragma unroll
    for (int off = 8; off; off >>= 1) {
        st += __shfl_xor(st, off);
        s0 += __shfl_xor(s0, off);
        s1 += __shfl_xor(s1, off);
    }
    float ot  = lt - mt - __logf(st);
    float o0  = l0 - m0 - __logf(s0);
    float o1  = l1 - m1 - __logf(s1);
    if (lane < 16) {
        size_t base = (size_t)n * 16 + j;
        outp[0 * 800000 + base] = ot;
        outp[1 * 800000 + base] = 0.5f * (o0 + o1);
        outp[2 * 800000 + base] = o0;
        outp[3 * 800000 + base] = o1;
    }
}

// ---------------- host launcher ----------------
extern "C" void kernel_launch(void* const* d_in, const int* in_sizes, int n_in,
                              void* d_out, int out_size, void* d_ws, size_t ws_size,
                              hipStream_t stream)
{
    const float* x          = (const float*)d_in[0];
    const int*   rows       = (const int*)d_in[1];
    const int*   cols       = (const int*)d_in[2];
    const float* vals       = (const float*)d_in[3];
    const float* fc_w       = (const float*)d_in[4];
    const float* fc_b       = (const float*)d_in[5];
    const float* conv_w     = (const float*)d_in[6];
    const float* att_conv_w = (const float*)d_in[7];
    const float* att_fc_w   = (const float*)d_in[8];
    const float* att_fc_b   = (const float*)d_in[9];
    const float* att_mix_w  = (const float*)d_in[10];
    const float* out_w      = (const float*)d_in[11];
    const float* out_b      = (const float*)d_in[12];
    float* outp = (float*)d_out;

    const size_t SB = (size_t)N_NODES * 128;     // 6.4M floats per buffer
    float* ws     = (float*)d_ws;
    float* B_h0a  = ws + 0 * SB;
    float* B_h0b  = ws + 1 * SB;
    float* B_hA   = ws + 2 * SB;
    float* B_hB   = ws + 3 * SB;
    float* B_a    = ws + 4 * SB;
    float* B_hi   = ws + 5 * SB;   // doubles as x2 scratch
    float* B_watt = ws + 6 * SB;
    float* WoT    = ws + 7 * SB;   // 4 * 16384 floats

    static const float thetas[4] = {0.40546511f, 0.22314355f, 0.15415068f, 0.11778304f};

    // per-layer orthonormalized weights (transposed)
    ortho_kernel<<<4, 256, 0, stream>>>(conv_w, WoT);

    // input FC for both views
    fc_relu_kernel<<<1563, 256, 0, stream>>>(x, fc_w, fc_b, B_h0a, B_hA, N_NODES);
    fc_relu_kernel<<<1563, 256, 0, stream>>>(x + (size_t)N_NODES * F_IN,
                                             fc_w + 128 * F_IN, fc_b + 128,
                                             B_h0b, B_hB, N_NODES);

    for (int i = 0; i < 4; ++i) {
        // ---- view 0: attention ----
        gemm128_kernel<0><<<782, 256, 0, stream>>>(B_hA, nullptr,
                                                   att_fc_w + (size_t)i * 16384,
                                                   att_fc_b + i * 128, nullptr,
                                                   B_hi, 1.f, 0.f, 0.f, N_NODES);
        att_kernel<<<25000, 256, 0, stream>>>(B_hA, B_hi, att_conv_w + i * 5,
                                              att_mix_w + i, B_watt, B_a, N_NODES);
        // ---- view 0: GCN layer ----
        hipMemsetAsync(B_hi, 0, SB * sizeof(float), stream);
        spmm_atomic_kernel<<<100000, 256, 0, stream>>>(rows, cols, vals, B_a, B_hi, N_EDGES);
        gemm128_kernel<1><<<782, 256, 0, stream>>>(B_hi, B_h0a, WoT + (size_t)i * 16384,
                                                   nullptr, nullptr, B_hA,
                                                   0.9f, 0.1f, thetas[i], N_NODES);
        // ---- view 1: GCN layer (then * w_att) ----
        hipMemsetAsync(B_hi, 0, SB * sizeof(float), stream);
        spmm_atomic_kernel<<<100000, 256, 0, stream>>>(rows + N_EDGES, cols + N_EDGES,
                                                       vals + N_EDGES, B_hB, B_hi, N_EDGES);
        gemm128_kernel<1><<<782, 256, 0, stream>>>(B_hi, B_h0b, WoT + (size_t)i * 16384,
                                                   nullptr, B_watt, B_hB,
                                                   0.9f, 0.1f, thetas[i], N_NODES);
    }

    out_kernel<<<12500, 256, 0, stream>>>(B_hA, B_hB, out_w, out_b, outp, N_NODES);
}

// Round 6
// 3477.610 us; speedup vs baseline: 3.8802x; 3.8802x over previous
//
#include <hip/hip_runtime.h>
#include <math.h>

// ---------------- problem constants ----------------
static const int N_NODES = 50000;
static const int N_EDGES = 800000;
static const int F_IN    = 500;
static const int C_DIM   = 128;

__device__ __forceinline__ float sigmoidf_(float x) { return 1.f / (1.f + __expf(-x)); }

// ---------------- ortho-norm (per-layer 128x128 cholesky + solve) ----------------
__global__ __launch_bounds__(256) void ortho_kernel(const float* __restrict__ conv_w,
                                                    float* __restrict__ woT)
{
    __shared__ float Wm[128][129];
    __shared__ float Am[128][129];
    const int li  = blockIdx.x;
    const int tid = threadIdx.x;
    const float* W = conv_w + (size_t)li * 16384;

    for (int idx = tid; idx < 16384; idx += 256) {
        int r = idx >> 7, c = idx & 127;
        Wm[r][c] = W[idx];
    }
    __syncthreads();
    for (int idx = tid; idx < 16384; idx += 256) {
        int i = idx >> 7, j = idx & 127;
        float s = 0.f;
        for (int k = 0; k < 128; ++k) s += Wm[k][i] * Wm[k][j];
        if (i == j) s += 1e-4f;
        Am[i][j] = s;
    }
    __syncthreads();
    for (int k = 0; k < 128; ++k) {
        if (tid == 0) Am[k][k] = sqrtf(Am[k][k]);
        __syncthreads();
        float dinv = 1.f / Am[k][k];
        for (int i = k + 1 + tid; i < 128; i += 256) Am[i][k] *= dinv;
        __syncthreads();
        for (int idx = tid; idx < 16384; idx += 256) {
            int i = idx >> 7, j = idx & 127;
            if (i > k && j > k && j <= i) Am[i][j] -= Am[i][k] * Am[j][k];
        }
        __syncthreads();
    }
    if (tid < 128) {
        int j = tid;
        for (int k = 0; k < 128; ++k) {
            float v = Wm[j][k];
            for (int m = 0; m < k; ++m) v -= Am[k][m] * Wm[j][m];
            Wm[j][k] = v / Am[k][k];
        }
    }
    __syncthreads();
    float* o = woT + (size_t)li * 16384;
    for (int idx = tid; idx < 16384; idx += 256) {
        int j = idx >> 7, k = idx & 127;
        o[idx] = Wm[k][j];
    }
}

// ---------------- input FC: h0 = relu(x @ w.T + b), duplicated to two buffers ----------------
__global__ __launch_bounds__(256) void fc_relu_kernel(const float* __restrict__ x,
                                                      const float* __restrict__ w,
                                                      const float* __restrict__ b,
                                                      float* __restrict__ h0,
                                                      float* __restrict__ h1,
                                                      int nrows)
{
    __shared__ float ws[128][101];
    __shared__ float xs[32][101];
    const int tid = threadIdx.x;
    const int n0  = blockIdx.x * 32;
    const int cq  = tid & 31;
    const int rh  = tid >> 5;
    float acc[4][4] = {};

    for (int kc = 0; kc < 500; kc += 100) {
        for (int idx = tid; idx < 12800; idx += 256) {
            int j = idx / 100, k = idx % 100;
            ws[j][k] = w[j * 500 + kc + k];
        }
        for (int idx = tid; idx < 3200; idx += 256) {
            int r = idx / 100, k = idx % 100;
            int n = n0 + r;
            xs[r][k] = (n < nrows) ? x[(size_t)n * 500 + kc + k] : 0.f;
        }
        __syncthreads();
        for (int k = 0; k < 100; ++k) {
            float b0 = ws[cq][k], b1 = ws[cq + 32][k], b2 = ws[cq + 64][k], b3 = ws[cq + 96][k];
#pragma unroll
            for (int rr = 0; rr < 4; ++rr) {
                float a = xs[rh * 4 + rr][k];
                acc[rr][0] += a * b0; acc[rr][1] += a * b1;
                acc[rr][2] += a * b2; acc[rr][3] += a * b3;
            }
        }
        __syncthreads();
    }
#pragma unroll
    for (int rr = 0; rr < 4; ++rr) {
        int n = n0 + rh * 4 + rr;
        if (n >= nrows) continue;
#pragma unroll
        for (int ci = 0; ci < 4; ++ci) {
            int j = cq + 32 * ci;
            float v = fmaxf(acc[rr][ci] + b[j], 0.f);
            h0[(size_t)n * 128 + j] = v;
            h1[(size_t)n * 128 + j] = v;
        }
    }
}

// ---------------- generic 128x128 GEMM ----------------
// MODE 0: out = A0 @ BwT + bias
// MODE 1: support = c0*A0 + c1*A1; out = relu(tanh(theta*(support@BwT) + (1-theta)*support)) [* watt]
template <int MODE>
__global__ __launch_bounds__(256) void gemm128_kernel(const float* __restrict__ A0,
                                                      const float* __restrict__ A1,
                                                      const float* __restrict__ Bw,
                                                      const float* __restrict__ bias,
                                                      const float* __restrict__ watt,
                                                      float* __restrict__ outp,
                                                      float c0, float c1, float theta,
                                                      int nrows)
{
    __shared__ float Bs[128][65];
    __shared__ float As[64][65];
    const int tid = threadIdx.x;
    const int n0  = blockIdx.x * 64;
    const int cq  = tid & 31;
    const int rh  = tid >> 5;
    float acc[8][4] = {};

    for (int kc = 0; kc < 128; kc += 64) {
        for (int idx = tid; idx < 128 * 64; idx += 256) {
            int j = idx >> 6, k = idx & 63;
            Bs[j][k] = Bw[j * 128 + kc + k];
        }
        for (int idx = tid; idx < 64 * 64; idx += 256) {
            int r = idx >> 6, k = idx & 63;
            int n = n0 + r;
            float v = 0.f;
            if (n < nrows) {
                v = c0 * A0[(size_t)n * 128 + kc + k];
                if (MODE == 1) v += c1 * A1[(size_t)n * 128 + kc + k];
            }
            As[r][k] = v;
        }
        __syncthreads();
        for (int k = 0; k < 64; ++k) {
            float b0 = Bs[cq][k], b1 = Bs[cq + 32][k], b2 = Bs[cq + 64][k], b3 = Bs[cq + 96][k];
#pragma unroll
            for (int rr = 0; rr < 8; ++rr) {
                float a = As[rh * 8 + rr][k];
                acc[rr][0] += a * b0; acc[rr][1] += a * b1;
                acc[rr][2] += a * b2; acc[rr][3] += a * b3;
            }
        }
        __syncthreads();
    }
#pragma unroll
    for (int rr = 0; rr < 8; ++rr) {
        int n = n0 + rh * 8 + rr;
        if (n >= nrows) continue;
#pragma unroll
        for (int ci = 0; ci < 4; ++ci) {
            int j = cq + 32 * ci;
            float v = acc[rr][ci];
            if (MODE == 0) {
                v += bias[j];
            } else {
                float s = c0 * A0[(size_t)n * 128 + j] + c1 * A1[(size_t)n * 128 + j];
                v = theta * v + (1.f - theta) * s;
                v = tanhf(v);
                v = fmaxf(v, 0.f);
                if (watt) v *= watt[(size_t)n * 128 + j];
            }
            outp[(size_t)n * 128 + j] = v;
        }
    }
}

// ---------------- attention elementwise (view 0) — writes hout IN-PLACE over h ----------------
// Safe: every read of h completes into regs/LDS before the write; strictly elementwise per (n,c).
__global__ __launch_bounds__(256) void att_kernel(float* __restrict__ h,
                                                  const float* __restrict__ x2g,
                                                  const float* __restrict__ cw,
                                                  const float* __restrict__ mwp,
                                                  float* __restrict__ watt,
                                                  int nrows)
{
    __shared__ float hrow[2][132];
    __shared__ float orow[2][132];
    __shared__ float red[2][2][2];
    const int tid = threadIdx.x;
    const int c   = tid & 127;
    const int rl  = tid >> 7;
    const int n   = blockIdx.x * 2 + rl;
    const bool valid = n < nrows;
    float hv = 0.f, x2v = 0.f;
    if (valid) { hv = h[(size_t)n * 128 + c]; x2v = x2g[(size_t)n * 128 + c]; }
    hrow[rl][c + 2] = hv;
    if (c < 2) { hrow[rl][c] = 0.f; hrow[rl][c + 130] = 0.f; }
    const float w0 = cw[0], w1 = cw[1], w2 = cw[2], w3 = cw[3], w4 = cw[4];
    __syncthreads();
    float x1 = w0 * hrow[rl][c] + w1 * hrow[rl][c + 1] + w2 * hrow[rl][c + 2]
             + w3 * hrow[rl][c + 3] + w4 * hrow[rl][c + 4];
    float p1 = x1, p2 = x2v;
#pragma unroll
    for (int off = 32; off; off >>= 1) { p1 += __shfl_xor(p1, off); p2 += __shfl_xor(p2, off); }
    int wir = (tid >> 6) & 1;
    if ((tid & 63) == 0) { red[rl][0][wir] = p1; red[rl][1][wir] = p2; }
    __syncthreads();
    float s1 = red[rl][0][0] + red[rl][0][1];
    float s2 = red[rl][1][0] + red[rl][1][1];
    float m  = sigmoidf_(mwp[0]);
    float o  = m * sigmoidf_(s1 * x2v) + (1.f - m) * sigmoidf_(s2 * x1);
    orow[rl][c + 2] = o;
    if (c < 2) { orow[rl][c] = 0.f; orow[rl][c + 130] = 0.f; }
    __syncthreads();
    float wv = w0 * orow[rl][c] + w1 * orow[rl][c + 1] + w2 * orow[rl][c + 2]
             + w3 * orow[rl][c + 3] + w4 * orow[rl][c + 4];
    wv = sigmoidf_(wv);
    if (valid) {
        watt[(size_t)n * 128 + c] = wv;
        h[(size_t)n * 128 + c]    = hv * wv;   // in-place gated h
    }
}

// ================= CSR build (counting sort by destination row) =================
// rcnt layout: [2][N_NODES] ints. hist -> counts; scan -> exclusive prefix (row start);
// scatter bumps to row end. spmm uses beg = rcnt[r-1] (or 0), end = rcnt[r].

__global__ __launch_bounds__(256) void hist_kernel(const int* __restrict__ rows,
                                                   int* __restrict__ rcnt)
{
    int gid = blockIdx.x * 256 + threadIdx.x;
    if (gid >= 2 * N_EDGES) return;
    int vsel = (gid >= N_EDGES) ? 1 : 0;
    atomicAdd(&rcnt[vsel * N_NODES + rows[gid]], 1);
}

// in-place exclusive prefix sum over each view's 50000 counters (1 block per view)
__global__ __launch_bounds__(1024) void scan_kernel(int* __restrict__ rcnt)
{
    __shared__ int s[2][1024];
    int* c = rcnt + blockIdx.x * N_NODES;
    const int tid = threadIdx.x;
    int running = 0;
    for (int base = 0; base < N_NODES; base += 1024) {
        int idx = base + tid;
        int val = (idx < N_NODES) ? c[idx] : 0;
        int buf = 0;
        s[0][tid] = val;
        __syncthreads();
#pragma unroll
        for (int off = 1; off < 1024; off <<= 1) {
            int t = s[buf][tid];
            if (tid >= off) t += s[buf][tid - off];
            s[buf ^ 1][tid] = t;
            buf ^= 1;
            __syncthreads();
        }
        int excl = s[buf][tid] - val;
        if (idx < N_NODES) c[idx] = running + excl;
        running += s[buf][1023];
        __syncthreads();
    }
}

__global__ __launch_bounds__(256) void scatter_kernel(const int* __restrict__ rows,
                                                      const int* __restrict__ cols,
                                                      const float* __restrict__ vals,
                                                      int* __restrict__ rcnt,
                                                      int* __restrict__ scol,
                                                      float* __restrict__ sval)
{
    int gid = blockIdx.x * 256 + threadIdx.x;
    if (gid >= 2 * N_EDGES) return;
    int vsel = (gid >= N_EDGES) ? 1 : 0;
    int pos = atomicAdd(&rcnt[vsel * N_NODES + rows[gid]], 1);   // pos in [0, N_EDGES)
    scol[vsel * N_EDGES + pos] = cols[gid];
    sval[vsel * N_EDGES + pos] = vals[gid];
}

// ---------------- SpMM gather: one row per 32-lane half-wave, 4 ch/lane ----------------
__global__ __launch_bounds__(256) void spmm_csr_kernel(const int* __restrict__ rend,
                                                       const int* __restrict__ scol,
                                                       const float* __restrict__ sval,
                                                       const float* __restrict__ h,
                                                       float* __restrict__ hi)
{
    const int tid  = threadIdx.x;
    const int row  = blockIdx.x * 8 + (tid >> 5);
    if (row >= N_NODES) return;
    const int lane = tid & 31;
    const int c0   = lane * 4;
    const int beg  = (row == 0) ? 0 : rend[row - 1];
    const int end  = rend[row];
    float4 acc = {0.f, 0.f, 0.f, 0.f};
    for (int e = beg; e < end; ++e) {
        int   c = scol[e];
        float v = sval[e];
        const float4 hv = *reinterpret_cast<const float4*>(&h[(size_t)c * 128 + c0]);
        acc.x += v * hv.x; acc.y += v * hv.y; acc.z += v * hv.z; acc.w += v * hv.w;
    }
    *reinterpret_cast<float4*>(&hi[(size_t)row * 128 + c0]) = acc;
}

// ---------------- final: logits (both views), 4x log-softmax outputs ----------------
__global__ __launch_bounds__(256) void out_kernel(const float* __restrict__ hA,
                                                  const float* __restrict__ hB,
                                                  const float* __restrict__ ow,
                                                  const float* __restrict__ ob,
                                                  float* __restrict__ outp,
                                                  int nrows)
{
    const int tid  = threadIdx.x;
    const int lane = tid & 63;
    const int wid  = tid >> 6;
    const int n    = blockIdx.x * 4 + wid;
    if (n >= nrows) return;
    const int j   = lane & 15;
    const int seg = lane >> 4;
    const float* a  = &hA[(size_t)n * 128 + seg * 32];
    const float* bx = &hB[(size_t)n * 128 + seg * 32];
    const float* wj = &ow[j * 128 + seg * 32];
    float d0 = 0.f, d1 = 0.f;
#pragma unroll
    for (int k = 0; k < 32; ++k) { float wv = wj[k]; d0 += a[k] * wv; d1 += bx[k] * wv; }
    d0 += __shfl_xor(d0, 16); d0 += __shfl_xor(d0, 32);
    d1 += __shfl_xor(d1, 16); d1 += __shfl_xor(d1, 32);
    float bias = ob[j];
    float l0 = d0 + bias, l1 = d1 + bias, lt = l0 + l1;

    float mt = lt, m0 = l0, m1 = l1;
#pragma unroll
    for (int off = 8; off; off >>= 1) {
        mt = fmaxf(mt, __shfl_xor(mt, off));
        m0 = fmaxf(m0, __shfl_xor(m0, off));
        m1 = fmaxf(m1, __shfl_xor(m1, off));
    }
    float et = __expf(lt - mt), e0 = __expf(l0 - m0), e1 = __expf(l1 - m1);
    float st = et, s0 = e0, s1 = e1;
#pragma unroll
    for (int off = 8; off; off >>= 1) {
        st += __shfl_xor(st, off);
        s0 += __shfl_xor(s0, off);
        s1 += __shfl_xor(s1, off);
    }
    float ot  = lt - mt - __logf(st);
    float o0  = l0 - m0 - __logf(s0);
    float o1  = l1 - m1 - __logf(s1);
    if (lane < 16) {
        size_t base = (size_t)n * 16 + j;
        outp[0 * 800000 + base] = ot;
        outp[1 * 800000 + base] = 0.5f * (o0 + o1);
        outp[2 * 800000 + base] = o0;
        outp[3 * 800000 + base] = o1;
    }
}

// ---------------- host launcher ----------------
extern "C" void kernel_launch(void* const* d_in, const int* in_sizes, int n_in,
                              void* d_out, int out_size, void* d_ws, size_t ws_size,
                              hipStream_t stream)
{
    const float* x          = (const float*)d_in[0];
    const int*   rows       = (const int*)d_in[1];
    const int*   cols       = (const int*)d_in[2];
    const float* vals       = (const float*)d_in[3];
    const float* fc_w       = (const float*)d_in[4];
    const float* fc_b       = (const float*)d_in[5];
    const float* conv_w     = (const float*)d_in[6];
    const float* att_conv_w = (const float*)d_in[7];
    const float* att_fc_w   = (const float*)d_in[8];
    const float* att_fc_b   = (const float*)d_in[9];
    const float* att_mix_w  = (const float*)d_in[10];
    const float* out_w      = (const float*)d_in[11];
    const float* out_b      = (const float*)d_in[12];
    float* outp = (float*)d_out;

    // ws budget (floats): 6*SB (153.6MB) + WoT (0.26MB) + CSR (13.2MB) = 167.1MB
    // < 179.5MB watermark proven safe in round 4.
    const size_t SB = (size_t)N_NODES * 128;
    float* ws     = (float*)d_ws;
    float* B_h0a  = ws + 0 * SB;
    float* B_h0b  = ws + 1 * SB;
    float* B_hA   = ws + 2 * SB;   // h (view0); gated in-place by att_kernel
    float* B_hB   = ws + 3 * SB;   // h (view1)
    float* B_hi   = ws + 4 * SB;   // x2 scratch + spmm output
    float* B_watt = ws + 5 * SB;
    float* WoT    = ws + 6 * SB;   // 4 * 16384 floats
    float* csr0   = WoT + 4 * 16384;
    int*   rcnt   = (int*)csr0;                       // [2][N_NODES]
    int*   scol   = (int*)(csr0 + 2 * N_NODES);       // [2][N_EDGES]
    float* sval   = csr0 + 2 * N_NODES + 2 * N_EDGES; // [2][N_EDGES]

    static const float thetas[4] = {0.40546511f, 0.22314355f, 0.15415068f, 0.11778304f};

    // ---- CSR build (both views) ----
    hipMemsetAsync(rcnt, 0, 2 * N_NODES * sizeof(int), stream);
    hist_kernel<<<6250, 256, 0, stream>>>(rows, rcnt);
    scan_kernel<<<2, 1024, 0, stream>>>(rcnt);
    scatter_kernel<<<6250, 256, 0, stream>>>(rows, cols, vals, rcnt, scol, sval);

    // per-layer orthonormalized weights (transposed)
    ortho_kernel<<<4, 256, 0, stream>>>(conv_w, WoT);

    // input FC for both views
    fc_relu_kernel<<<1563, 256, 0, stream>>>(x, fc_w, fc_b, B_h0a, B_hA, N_NODES);
    fc_relu_kernel<<<1563, 256, 0, stream>>>(x + (size_t)N_NODES * F_IN,
                                             fc_w + 128 * F_IN, fc_b + 128,
                                             B_h0b, B_hB, N_NODES);

    for (int i = 0; i < 4; ++i) {
        // ---- view 0: attention (x2 into B_hi, then gate B_hA in-place) ----
        gemm128_kernel<0><<<782, 256, 0, stream>>>(B_hA, nullptr,
                                                   att_fc_w + (size_t)i * 16384,
                                                   att_fc_b + i * 128, nullptr,
                                                   B_hi, 1.f, 0.f, 0.f, N_NODES);
        att_kernel<<<25000, 256, 0, stream>>>(B_hA, B_hi, att_conv_w + i * 5,
                                              att_mix_w + i, B_watt, N_NODES);
        // ---- view 0: GCN layer ----
        spmm_csr_kernel<<<6250, 256, 0, stream>>>(rcnt, scol, sval, B_hA, B_hi);
        gemm128_kernel<1><<<782, 256, 0, stream>>>(B_hi, B_h0a, WoT + (size_t)i * 16384,
                                                   nullptr, nullptr, B_hA,
                                                   0.9f, 0.1f, thetas[i], N_NODES);
        // ---- view 1: GCN layer (then * w_att) ----
        spmm_csr_kernel<<<6250, 256, 0, stream>>>(rcnt + N_NODES, scol + N_EDGES,
                                                  sval + N_EDGES, B_hB, B_hi);
        gemm128_kernel<1><<<782, 256, 0, stream>>>(B_hi, B_h0b, WoT + (size_t)i * 16384,
                                                   nullptr, B_watt, B_hB,
                                                   0.9f, 0.1f, thetas[i], N_NODES);
    }

    out_kernel<<<12500, 256, 0, stream>>>(B_hA, B_hB, out_w, out_b, outp, N_NODES);
}

// Round 7
// 2329.326 us; speedup vs baseline: 5.7930x; 1.4930x over previous
//
#include <hip/hip_runtime.h>
#include <hip/hip_bf16.h>
#include <math.h>

// ---------------- problem constants ----------------
static const int N_NODES = 50000;
static const int N_EDGES = 800000;
static const int F_IN    = 500;
static const int C_DIM   = 128;

using bf16x8 = __attribute__((ext_vector_type(8))) short;   // 8 bf16 in 4 VGPRs
using f32x4  = __attribute__((ext_vector_type(4))) float;   // MFMA accumulator

__device__ __forceinline__ float sigmoidf_(float x) { return 1.f / (1.f + __expf(-x)); }

__device__ __forceinline__ unsigned short f2bf(float f) {
    __hip_bfloat16 h = __float2bfloat16(f);
    unsigned short u;
    __builtin_memcpy(&u, &h, 2);
    return u;
}

// ---------------- ortho-norm (per-layer 128x128 cholesky + solve) ----------------
// WoT[li][j*128+k] = Wo[k][j].  Restructured: 4x4-tiled WtW, diag in diagL (no race),
// 2 barriers/iter, update restricted to rows > k.
__global__ __launch_bounds__(256) void ortho_kernel(const float* __restrict__ conv_w,
                                                    float* __restrict__ woT)
{
    __shared__ float Wm[128][129];
    __shared__ float Am[128][129];
    __shared__ float diagL[128];
    const int li  = blockIdx.x;
    const int tid = threadIdx.x;
    const float* W = conv_w + (size_t)li * 16384;

    for (int idx = tid; idx < 16384; idx += 256) {
        int r = idx >> 7, c = idx & 127;
        Wm[r][c] = W[idx];
    }
    __syncthreads();

    // A = W^T W + 1e-4 I, 4x4 register tiles (32x32 tiles, 4 per thread)
    for (int t = tid; t < 1024; t += 256) {
        const int i0 = (t >> 5) << 2;
        const int j0 = (t & 31) << 2;
        float a[4][4] = {};
        for (int k = 0; k < 128; ++k) {
            float wi0 = Wm[k][i0], wi1 = Wm[k][i0 + 1], wi2 = Wm[k][i0 + 2], wi3 = Wm[k][i0 + 3];
            float wj0 = Wm[k][j0], wj1 = Wm[k][j0 + 1], wj2 = Wm[k][j0 + 2], wj3 = Wm[k][j0 + 3];
            a[0][0] += wi0 * wj0; a[0][1] += wi0 * wj1; a[0][2] += wi0 * wj2; a[0][3] += wi0 * wj3;
            a[1][0] += wi1 * wj0; a[1][1] += wi1 * wj1; a[1][2] += wi1 * wj2; a[1][3] += wi1 * wj3;
            a[2][0] += wi2 * wj0; a[2][1] += wi2 * wj1; a[2][2] += wi2 * wj2; a[2][3] += wi2 * wj3;
            a[3][0] += wi3 * wj0; a[3][1] += wi3 * wj1; a[3][2] += wi3 * wj2; a[3][3] += wi3 * wj3;
        }
#pragma unroll
        for (int r = 0; r < 4; ++r)
#pragma unroll
            for (int c = 0; c < 4; ++c)
                Am[i0 + r][j0 + c] = a[r][c] + ((i0 + r == j0 + c) ? 1e-4f : 0.f);
    }
    __syncthreads();

    // right-looking cholesky; diag kept in diagL, Am[k][k] never overwritten
    for (int k = 0; k < 128; ++k) {
        float akk  = Am[k][k];
        float dinv = 1.f / sqrtf(akk);
        if (tid == 0) diagL[k] = sqrtf(akk);
        int i = k + 1 + tid;
        if (i < 128) Am[i][k] *= dinv;
        __syncthreads();
        const int R = 127 - k;
        for (int idx = tid; idx < (R << 7); idx += 256) {
            int i2 = k + 1 + (idx >> 7);
            int j  = idx & 127;
            if (j > k && j <= i2) Am[i2][j] = fmaf(-Am[i2][k], Am[j][k], Am[i2][j]);
        }
        __syncthreads();
    }

    // forward solve L Y = W^T ; store Y[k][j] into Wm[j][k] (thread j owns row j)
    if (tid < 128) {
        int j = tid;
        for (int k = 0; k < 128; ++k) {
            float v = Wm[j][k];
            for (int m = 0; m < k; ++m) v = fmaf(-Am[k][m], Wm[j][m], v);
            Wm[j][k] = v / diagL[k];
        }
    }
    __syncthreads();
    float* o = woT + (size_t)li * 16384;
    for (int idx = tid; idx < 16384; idx += 256) {
        int j = idx >> 7, k = idx & 127;
        o[idx] = Wm[k][j];
    }
}

// ================= bf16 MFMA GEMMs =================
// Block: 64 rows x 128 cols, 256 threads = 4 waves, wave w owns rows [16w,16w+16).
// LDS bf16 tiles padded to 136 elems/row (272B stride -> 2-way conflicts only).
// mfma_f32_16x16x32_bf16: A[row=l&15][k=(l>>4)*8+e], B[k=(l>>4)*8+e][col=l&15],
// C/D: col=l&15, row=(l>>4)*4+reg  [verified layout].

// ---- input FC: h0 = relu(x @ w.T + b) -> two buffers; K=500 padded to 512 ----
__global__ __launch_bounds__(256) void fc_relu_mfma_kernel(const float* __restrict__ x,
                                                           const float* __restrict__ w,
                                                           const float* __restrict__ b,
                                                           float* __restrict__ h0,
                                                           float* __restrict__ h1,
                                                           int nrows)
{
    __shared__ unsigned short Asm[64 * 136];
    __shared__ unsigned short Bsm[128 * 136];
    const int tid  = threadIdx.x;
    const int n0   = blockIdx.x * 64;
    const int lane = tid & 63;
    const int wv   = tid >> 6;
    const int lrow = lane & 15;
    const int kgrp = lane >> 4;

    f32x4 acc[8];
#pragma unroll
    for (int t = 0; t < 8; ++t) acc[t] = (f32x4){0.f, 0.f, 0.f, 0.f};

    for (int kc = 0; kc < 512; kc += 128) {
        // stage B chunk: w[j][kc..kc+128)
        for (int cid = tid; cid < 128 * 16; cid += 256) {
            int r = cid >> 4, c8 = cid & 15;
            int kg = kc + c8 * 8;
            union { unsigned short u[8]; bf16x8 v; } t;
            if (kg + 8 <= 500) {
                const float* src = &w[r * 500 + kg];
                float4 v0 = *reinterpret_cast<const float4*>(src);
                float4 v1 = *reinterpret_cast<const float4*>(src + 4);
                t.u[0]=f2bf(v0.x); t.u[1]=f2bf(v0.y); t.u[2]=f2bf(v0.z); t.u[3]=f2bf(v0.w);
                t.u[4]=f2bf(v1.x); t.u[5]=f2bf(v1.y); t.u[6]=f2bf(v1.z); t.u[7]=f2bf(v1.w);
            } else {
#pragma unroll
                for (int e = 0; e < 8; ++e)
                    t.u[e] = (kg + e < 500) ? f2bf(w[r * 500 + kg + e]) : (unsigned short)0;
            }
            *reinterpret_cast<bf16x8*>(&Bsm[r * 136 + c8 * 8]) = t.v;
        }
        // stage A chunk: x[n][kc..kc+128)
        for (int cid = tid; cid < 64 * 16; cid += 256) {
            int r = cid >> 4, c8 = cid & 15;
            int n = n0 + r;
            int kg = kc + c8 * 8;
            union { unsigned short u[8]; bf16x8 v; } t;
            if (n < nrows && kg + 8 <= 500) {
                const float* src = &x[(size_t)n * 500 + kg];
                float4 v0 = *reinterpret_cast<const float4*>(src);
                float4 v1 = *reinterpret_cast<const float4*>(src + 4);
                t.u[0]=f2bf(v0.x); t.u[1]=f2bf(v0.y); t.u[2]=f2bf(v0.z); t.u[3]=f2bf(v0.w);
                t.u[4]=f2bf(v1.x); t.u[5]=f2bf(v1.y); t.u[6]=f2bf(v1.z); t.u[7]=f2bf(v1.w);
            } else if (n < nrows) {
#pragma unroll
                for (int e = 0; e < 8; ++e)
                    t.u[e] = (kg + e < 500) ? f2bf(x[(size_t)n * 500 + kg + e]) : (unsigned short)0;
            } else {
#pragma unroll
                for (int e = 0; e < 8; ++e) t.u[e] = 0;
            }
            *reinterpret_cast<bf16x8*>(&Asm[r * 136 + c8 * 8]) = t.v;
        }
        __syncthreads();
#pragma unroll
        for (int kt = 0; kt < 4; ++kt) {
            int koff = kt * 32 + kgrp * 8;
            bf16x8 av = *reinterpret_cast<const bf16x8*>(&Asm[(wv * 16 + lrow) * 136 + koff]);
#pragma unroll
            for (int t = 0; t < 8; ++t) {
                bf16x8 bv = *reinterpret_cast<const bf16x8*>(&Bsm[(t * 16 + lrow) * 136 + koff]);
                acc[t] = __builtin_amdgcn_mfma_f32_16x16x32_bf16(av, bv, acc[t], 0, 0, 0);
            }
        }
        __syncthreads();
    }
#pragma unroll
    for (int t = 0; t < 8; ++t) {
        int j = t * 16 + lrow;
        float bj = b[j];
#pragma unroll
        for (int r = 0; r < 4; ++r) {
            int n = n0 + wv * 16 + kgrp * 4 + r;
            if (n < nrows) {
                float v = fmaxf(acc[t][r] + bj, 0.f);
                h0[(size_t)n * 128 + j] = v;
                h1[(size_t)n * 128 + j] = v;
            }
        }
    }
}

// ---- generic 128x128 GEMM, bf16 MFMA, f32 epilogue ----
// MODE 0: out = A0 @ BwT + bias
// MODE 1: support = c0*A0 + c1*A1 (staged bf16); out = relu(tanh(theta*acc + (1-theta)*support_f32)) [* watt]
template <int MODE>
__global__ __launch_bounds__(256) void gemm128_mfma_kernel(const float* __restrict__ A0,
                                                           const float* __restrict__ A1,
                                                           const float* __restrict__ Bw,
                                                           const float* __restrict__ bias,
                                                           const float* __restrict__ watt,
                                                           float* __restrict__ outp,
                                                           float c0, float c1, float theta,
                                                           int nrows)
{
    __shared__ unsigned short Asm[64 * 136];
    __shared__ unsigned short Bsm[128 * 136];
    const int tid  = threadIdx.x;
    const int n0   = blockIdx.x * 64;
    const int lane = tid & 63;
    const int wv   = tid >> 6;
    const int lrow = lane & 15;
    const int kgrp = lane >> 4;

    // stage B (weights 128x128)
    for (int cid = tid; cid < 128 * 16; cid += 256) {
        int r = cid >> 4, c8 = cid & 15;
        const float* src = &Bw[r * 128 + c8 * 8];
        float4 v0 = *reinterpret_cast<const float4*>(src);
        float4 v1 = *reinterpret_cast<const float4*>(src + 4);
        union { unsigned short u[8]; bf16x8 v; } t;
        t.u[0]=f2bf(v0.x); t.u[1]=f2bf(v0.y); t.u[2]=f2bf(v0.z); t.u[3]=f2bf(v0.w);
        t.u[4]=f2bf(v1.x); t.u[5]=f2bf(v1.y); t.u[6]=f2bf(v1.z); t.u[7]=f2bf(v1.w);
        *reinterpret_cast<bf16x8*>(&Bsm[r * 136 + c8 * 8]) = t.v;
    }
    // stage A (MODE1: support = c0*A0 + c1*A1)
    for (int cid = tid; cid < 64 * 16; cid += 256) {
        int r = cid >> 4, c8 = cid & 15;
        int n = n0 + r;
        union { unsigned short u[8]; bf16x8 v; } t;
        if (n < nrows) {
            const float* s0 = &A0[(size_t)n * 128 + c8 * 8];
            float4 a0 = *reinterpret_cast<const float4*>(s0);
            float4 a1 = *reinterpret_cast<const float4*>(s0 + 4);
            if (MODE == 1) {
                const float* s1 = &A1[(size_t)n * 128 + c8 * 8];
                float4 b0 = *reinterpret_cast<const float4*>(s1);
                float4 b1 = *reinterpret_cast<const float4*>(s1 + 4);
                a0.x = c0 * a0.x + c1 * b0.x; a0.y = c0 * a0.y + c1 * b0.y;
                a0.z = c0 * a0.z + c1 * b0.z; a0.w = c0 * a0.w + c1 * b0.w;
                a1.x = c0 * a1.x + c1 * b1.x; a1.y = c0 * a1.y + c1 * b1.y;
                a1.z = c0 * a1.z + c1 * b1.z; a1.w = c0 * a1.w + c1 * b1.w;
            }
            t.u[0]=f2bf(a0.x); t.u[1]=f2bf(a0.y); t.u[2]=f2bf(a0.z); t.u[3]=f2bf(a0.w);
            t.u[4]=f2bf(a1.x); t.u[5]=f2bf(a1.y); t.u[6]=f2bf(a1.z); t.u[7]=f2bf(a1.w);
        } else {
#pragma unroll
            for (int e = 0; e < 8; ++e) t.u[e] = 0;
        }
        *reinterpret_cast<bf16x8*>(&Asm[r * 136 + c8 * 8]) = t.v;
    }
    __syncthreads();

    f32x4 acc[8];
#pragma unroll
    for (int t = 0; t < 8; ++t) acc[t] = (f32x4){0.f, 0.f, 0.f, 0.f};
#pragma unroll
    for (int kt = 0; kt < 4; ++kt) {
        int koff = kt * 32 + kgrp * 8;
        bf16x8 av = *reinterpret_cast<const bf16x8*>(&Asm[(wv * 16 + lrow) * 136 + koff]);
#pragma unroll
        for (int t = 0; t < 8; ++t) {
            bf16x8 bv = *reinterpret_cast<const bf16x8*>(&Bsm[(t * 16 + lrow) * 136 + koff]);
            acc[t] = __builtin_amdgcn_mfma_f32_16x16x32_bf16(av, bv, acc[t], 0, 0, 0);
        }
    }

#pragma unroll
    for (int t = 0; t < 8; ++t) {
        int j = t * 16 + lrow;
#pragma unroll
        for (int r = 0; r < 4; ++r) {
            int n = n0 + wv * 16 + kgrp * 4 + r;
            if (n >= nrows) continue;
            float v = acc[t][r];
            if (MODE == 0) {
                v += bias[j];
            } else {
                float s = c0 * A0[(size_t)n * 128 + j] + c1 * A1[(size_t)n * 128 + j];
                v = theta * v + (1.f - theta) * s;
                v = tanhf(v);
                v = fmaxf(v, 0.f);
                if (watt) v *= watt[(size_t)n * 128 + j];
            }
            outp[(size_t)n * 128 + j] = v;
        }
    }
}

// ---------------- attention elementwise (view 0) — writes hout IN-PLACE over h ----------------
__global__ __launch_bounds__(256) void att_kernel(float* __restrict__ h,
                                                  const float* __restrict__ x2g,
                                                  const float* __restrict__ cw,
                                                  const float* __restrict__ mwp,
                                                  float* __restrict__ watt,
                                                  int nrows)
{
    __shared__ float hrow[2][132];
    __shared__ float orow[2][132];
    __shared__ float red[2][2][2];
    const int tid = threadIdx.x;
    const int c   = tid & 127;
    const int rl  = tid >> 7;
    const int n   = blockIdx.x * 2 + rl;
    const bool valid = n < nrows;
    float hv = 0.f, x2v = 0.f;
    if (valid) { hv = h[(size_t)n * 128 + c]; x2v = x2g[(size_t)n * 128 + c]; }
    hrow[rl][c + 2] = hv;
    if (c < 2) { hrow[rl][c] = 0.f; hrow[rl][c + 130] = 0.f; }
    const float w0 = cw[0], w1 = cw[1], w2 = cw[2], w3 = cw[3], w4 = cw[4];
    __syncthreads();
    float x1 = w0 * hrow[rl][c] + w1 * hrow[rl][c + 1] + w2 * hrow[rl][c + 2]
             + w3 * hrow[rl][c + 3] + w4 * hrow[rl][c + 4];
    float p1 = x1, p2 = x2v;
#pragma unroll
    for (int off = 32; off; off >>= 1) { p1 += __shfl_xor(p1, off); p2 += __shfl_xor(p2, off); }
    int wir = (tid >> 6) & 1;
    if ((tid & 63) == 0) { red[rl][0][wir] = p1; red[rl][1][wir] = p2; }
    __syncthreads();
    float s1 = red[rl][0][0] + red[rl][0][1];
    float s2 = red[rl][1][0] + red[rl][1][1];
    float m  = sigmoidf_(mwp[0]);
    float o  = m * sigmoidf_(s1 * x2v) + (1.f - m) * sigmoidf_(s2 * x1);
    orow[rl][c + 2] = o;
    if (c < 2) { orow[rl][c] = 0.f; orow[rl][c + 130] = 0.f; }
    __syncthreads();
    float wv = w0 * orow[rl][c] + w1 * orow[rl][c + 1] + w2 * orow[rl][c + 2]
             + w3 * orow[rl][c + 3] + w4 * orow[rl][c + 4];
    wv = sigmoidf_(wv);
    if (valid) {
        watt[(size_t)n * 128 + c] = wv;
        h[(size_t)n * 128 + c]    = hv * wv;
    }
}

// ================= CSR build (counting sort by destination row) =================
__global__ __launch_bounds__(256) void hist_kernel(const int* __restrict__ rows,
                                                   int* __restrict__ rcnt)
{
    int gid = blockIdx.x * 256 + threadIdx.x;
    if (gid >= 2 * N_EDGES) return;
    int vsel = (gid >= N_EDGES) ? 1 : 0;
    atomicAdd(&rcnt[vsel * N_NODES + rows[gid]], 1);
}

__global__ __launch_bounds__(1024) void scan_kernel(int* __restrict__ rcnt)
{
    __shared__ int s[2][1024];
    int* c = rcnt + blockIdx.x * N_NODES;
    const int tid = threadIdx.x;
    int running = 0;
    for (int base = 0; base < N_NODES; base += 1024) {
        int idx = base + tid;
        int val = (idx < N_NODES) ? c[idx] : 0;
        int buf = 0;
        s[0][tid] = val;
        __syncthreads();
#pragma unroll
        for (int off = 1; off < 1024; off <<= 1) {
            int t = s[buf][tid];
            if (tid >= off) t += s[buf][tid - off];
            s[buf ^ 1][tid] = t;
            buf ^= 1;
            __syncthreads();
        }
        int excl = s[buf][tid] - val;
        if (idx < N_NODES) c[idx] = running + excl;
        running += s[buf][1023];
        __syncthreads();
    }
}

__global__ __launch_bounds__(256) void scatter_kernel(const int* __restrict__ rows,
                                                      const int* __restrict__ cols,
                                                      const float* __restrict__ vals,
                                                      int* __restrict__ rcnt,
                                                      int* __restrict__ scol,
                                                      float* __restrict__ sval)
{
    int gid = blockIdx.x * 256 + threadIdx.x;
    if (gid >= 2 * N_EDGES) return;
    int vsel = (gid >= N_EDGES) ? 1 : 0;
    int pos = atomicAdd(&rcnt[vsel * N_NODES + rows[gid]], 1);
    scol[vsel * N_EDGES + pos] = cols[gid];
    sval[vsel * N_EDGES + pos] = vals[gid];
}

// ---------------- SpMM gather: one row per 32-lane half-wave, 4 ch/lane ----------------
__global__ __launch_bounds__(256) void spmm_csr_kernel(const int* __restrict__ rend,
                                                       const int* __restrict__ scol,
                                                       const float* __restrict__ sval,
                                                       const float* __restrict__ h,
                                                       float* __restrict__ hi)
{
    const int tid  = threadIdx.x;
    const int row  = blockIdx.x * 8 + (tid >> 5);
    if (row >= N_NODES) return;
    const int lane = tid & 31;
    const int c0   = lane * 4;
    const int beg  = (row == 0) ? 0 : rend[row - 1];
    const int end  = rend[row];
    float4 acc = {0.f, 0.f, 0.f, 0.f};
    for (int e = beg; e < end; ++e) {
        int   c = scol[e];
        float v = sval[e];
        const float4 hv = *reinterpret_cast<const float4*>(&h[(size_t)c * 128 + c0]);
        acc.x += v * hv.x; acc.y += v * hv.y; acc.z += v * hv.z; acc.w += v * hv.w;
    }
    *reinterpret_cast<float4*>(&hi[(size_t)row * 128 + c0]) = acc;
}

// ---------------- final: logits (both views), 4x log-softmax outputs ----------------
__global__ __launch_bounds__(256) void out_kernel(const float* __restrict__ hA,
                                                  const float* __restrict__ hB,
                                                  const float* __restrict__ ow,
                                                  const float* __restrict__ ob,
                                                  float* __restrict__ outp,
                                                  int nrows)
{
    const int tid  = threadIdx.x;
    const int lane = tid & 63;
    const int wid  = tid >> 6;
    const int n    = blockIdx.x * 4 + wid;
    if (n >= nrows) return;
    const int j   = lane & 15;
    const int seg = lane >> 4;
    const float* a  = &hA[(size_t)n * 128 + seg * 32];
    const float* bx = &hB[(size_t)n * 128 + seg * 32];
    const float* wj = &ow[j * 128 + seg * 32];
    float d0 = 0.f, d1 = 0.f;
#pragma unroll
    for (int k = 0; k < 32; ++k) { float wv = wj[k]; d0 += a[k] * wv; d1 += bx[k] * wv; }
    d0 += __shfl_xor(d0, 16); d0 += __shfl_xor(d0, 32);
    d1 += __shfl_xor(d1, 16); d1 += __shfl_xor(d1, 32);
    float bias = ob[j];
    float l0 = d0 + bias, l1 = d1 + bias, lt = l0 + l1;

    float mt = lt, m0 = l0, m1 = l1;
#pragma unroll
    for (int off = 8; off; off >>= 1) {
        mt = fmaxf(mt, __shfl_xor(mt, off));
        m0 = fmaxf(m0, __shfl_xor(m0, off));
        m1 = fmaxf(m1, __shfl_xor(m1, off));
    }
    float et = __expf(lt - mt), e0 = __expf(l0 - m0), e1 = __expf(l1 - m1);
    float st = et, s0 = e0, s1 = e1;
#pragma unroll
    for (int off = 8; off; off >>= 1) {
        st += __shfl_xor(st, off);
        s0 += __shfl_xor(s0, off);
        s1 += __shfl_xor(s1, off);
    }
    float ot  = lt - mt - __logf(st);
    float o0  = l0 - m0 - __logf(s0);
    float o1  = l1 - m1 - __logf(s1);
    if (lane < 16) {
        size_t base = (size_t)n * 16 + j;
        outp[0 * 800000 + base] = ot;
        outp[1 * 800000 + base] = 0.5f * (o0 + o1);
        outp[2 * 800000 + base] = o0;
        outp[3 * 800000 + base] = o1;
    }
}

// ---------------- host launcher ----------------
extern "C" void kernel_launch(void* const* d_in, const int* in_sizes, int n_in,
                              void* d_out, int out_size, void* d_ws, size_t ws_size,
                              hipStream_t stream)
{
    const float* x          = (const float*)d_in[0];
    const int*   rows       = (const int*)d_in[1];
    const int*   cols       = (const int*)d_in[2];
    const float* vals       = (const float*)d_in[3];
    const float* fc_w       = (const float*)d_in[4];
    const float* fc_b       = (const float*)d_in[5];
    const float* conv_w     = (const float*)d_in[6];
    const float* att_conv_w = (const float*)d_in[7];
    const float* att_fc_w   = (const float*)d_in[8];
    const float* att_fc_b   = (const float*)d_in[9];
    const float* att_mix_w  = (const float*)d_in[10];
    const float* out_w      = (const float*)d_in[11];
    const float* out_b      = (const float*)d_in[12];
    float* outp = (float*)d_out;

    // ws budget: 6*SB (153.6MB) + WoT (0.26MB) + CSR (13.2MB) = 167.1MB (< proven 179.5MB)
    const size_t SB = (size_t)N_NODES * 128;
    float* ws     = (float*)d_ws;
    float* B_h0a  = ws + 0 * SB;
    float* B_h0b  = ws + 1 * SB;
    float* B_hA   = ws + 2 * SB;   // h (view0); gated in-place by att_kernel
    float* B_hB   = ws + 3 * SB;   // h (view1)
    float* B_hi   = ws + 4 * SB;   // x2 scratch + spmm output
    float* B_watt = ws + 5 * SB;
    float* WoT    = ws + 6 * SB;   // 4 * 16384 floats
    float* csr0   = WoT + 4 * 16384;
    int*   rcnt   = (int*)csr0;                       // [2][N_NODES]
    int*   scol   = (int*)(csr0 + 2 * N_NODES);       // [2][N_EDGES]
    float* sval   = csr0 + 2 * N_NODES + 2 * N_EDGES; // [2][N_EDGES]

    static const float thetas[4] = {0.40546511f, 0.22314355f, 0.15415068f, 0.11778304f};

    // ---- CSR build (both views) ----
    hipMemsetAsync(rcnt, 0, 2 * N_NODES * sizeof(int), stream);
    hist_kernel<<<6250, 256, 0, stream>>>(rows, rcnt);
    scan_kernel<<<2, 1024, 0, stream>>>(rcnt);
    scatter_kernel<<<6250, 256, 0, stream>>>(rows, cols, vals, rcnt, scol, sval);

    // per-layer orthonormalized weights (transposed)
    ortho_kernel<<<4, 256, 0, stream>>>(conv_w, WoT);

    // input FC for both views (bf16 MFMA)
    fc_relu_mfma_kernel<<<782, 256, 0, stream>>>(x, fc_w, fc_b, B_h0a, B_hA, N_NODES);
    fc_relu_mfma_kernel<<<782, 256, 0, stream>>>(x + (size_t)N_NODES * F_IN,
                                                 fc_w + 128 * F_IN, fc_b + 128,
                                                 B_h0b, B_hB, N_NODES);

    for (int i = 0; i < 4; ++i) {
        // ---- view 0: attention (x2 into B_hi, then gate B_hA in-place) ----
        gemm128_mfma_kernel<0><<<782, 256, 0, stream>>>(B_hA, nullptr,
                                                        att_fc_w + (size_t)i * 16384,
                                                        att_fc_b + i * 128, nullptr,
                                                        B_hi, 1.f, 0.f, 0.f, N_NODES);
        att_kernel<<<25000, 256, 0, stream>>>(B_hA, B_hi, att_conv_w + i * 5,
                                              att_mix_w + i, B_watt, N_NODES);
        // ---- view 0: GCN layer ----
        spmm_csr_kernel<<<6250, 256, 0, stream>>>(rcnt, scol, sval, B_hA, B_hi);
        gemm128_mfma_kernel<1><<<782, 256, 0, stream>>>(B_hi, B_h0a, WoT + (size_t)i * 16384,
                                                        nullptr, nullptr, B_hA,
                                                        0.9f, 0.1f, thetas[i], N_NODES);
        // ---- view 1: GCN layer (then * w_att) ----
        spmm_csr_kernel<<<6250, 256, 0, stream>>>(rcnt + N_NODES, scol + N_EDGES,
                                                  sval + N_EDGES, B_hB, B_hi);
        gemm128_mfma_kernel<1><<<782, 256, 0, stream>>>(B_hi, B_h0b, WoT + (size_t)i * 16384,
                                                        nullptr, B_watt, B_hB,
                                                        0.9f, 0.1f, thetas[i], N_NODES);
    }

    out_kernel<<<12500, 256, 0, stream>>>(B_hA, B_hB, out_w, out_b, outp, N_NODES);
}

// Round 8
// 1981.283 us; speedup vs baseline: 6.8107x; 1.1757x over previous
//
#include <hip/hip_runtime.h>
#include <hip/hip_bf16.h>
#include <math.h>

// ---------------- problem constants ----------------
static const int N_NODES = 50000;
static const int N_EDGES = 800000;
static const int F_IN    = 500;
static const int C_DIM   = 128;

using bf16x8 = __attribute__((ext_vector_type(8))) short;   // 8 bf16 in 4 VGPRs
using f32x4  = __attribute__((ext_vector_type(4))) float;   // MFMA accumulator

__device__ __forceinline__ float sigmoidf_(float x) { return 1.f / (1.f + __expf(-x)); }

__device__ __forceinline__ unsigned short f2bf(float f) {
    __hip_bfloat16 h = __float2bfloat16(f);
    unsigned short u;
    __builtin_memcpy(&u, &h, 2);
    return u;
}

// ================= ortho-norm, restructured =================
// Phase 1 (full-chip parallel): A = W^T W + 1e-4 I  -> Am_g[4][128][128]
__global__ __launch_bounds__(256) void wtw_kernel(const float* __restrict__ conv_w,
                                                  float* __restrict__ Am_g)
{
    __shared__ float Wi[128][16];
    __shared__ float Wj[128][16];
    const int bid = blockIdx.x;
    const int li  = bid >> 6;
    const int t6  = bid & 63;
    const int ti  = (t6 >> 3) << 4;
    const int tj  = (t6 & 7) << 4;
    const int tid = threadIdx.x;
    const float* W = conv_w + (size_t)li * 16384;
    for (int idx = tid; idx < 2048; idx += 256) {
        int k = idx >> 4, c = idx & 15;
        Wi[k][c] = W[k * 128 + ti + c];
        Wj[k][c] = W[k * 128 + tj + c];
    }
    __syncthreads();
    const int i = tid >> 4, j = tid & 15;
    float acc = 0.f;
    for (int k = 0; k < 128; ++k) acc = fmaf(Wi[k][i], Wj[k][j], acc);
    if (ti + i == tj + j) acc += 1e-4f;
    Am_g[(size_t)li * 16384 + (ti + i) * 128 + tj + j] = acc;
}

// Phase 2 (4 blocks x 512): LDL^T-form elimination (1 barrier/iter, raw columns)
// + panel-blocked z-form solve. Writes WoT in bf16: WoT[a][b] = z[b][a]*sqrt(D[a]).
__global__ __launch_bounds__(512) void chol_solve_kernel(const float* __restrict__ Am_g,
                                                         const float* __restrict__ conv_w,
                                                         unsigned short* __restrict__ woT)
{
    __shared__ float Am[128][129];
    __shared__ float Wm[128][129];
    const int li  = blockIdx.x;
    const int tid = threadIdx.x;
    const float* Ag = Am_g  + (size_t)li * 16384;
    const float* Wg = conv_w + (size_t)li * 16384;
    for (int idx = tid; idx < 16384; idx += 512) {
        Am[idx >> 7][idx & 127] = Ag[idx];
        Wm[idx >> 7][idx & 127] = Wg[idx];
    }
    __syncthreads();

    // elimination: Am[i][j] -= Am[i][k]*(1/D_k)*Am[j][k], lower triangle, no scaling
    for (int k = 0; k < 127; ++k) {
        float rk = 1.f / Am[k][k];
        const int R = 127 - k;
        for (int idx = tid; idx < (R << 7); idx += 512) {
            int i2 = k + 1 + (idx >> 7);
            int j  = idx & 127;
            if (j > k && j <= i2)
                Am[i2][j] = fmaf(-Am[i2][k] * rk, Am[j][k], Am[i2][j]);
        }
        __syncthreads();
    }

    // panel-blocked forward solve (z-form): Wm[j][k] <- z_j[k]
    // z_j[k] = (W[j][k] - sum_{m<k} Am[k][m]*z_j[m]) / D[k]
    for (int p = 0; p < 4; ++p) {
        const int kbase = p * 32;
        if (p > 0) {
            // cross-panel correction: parallel over all 512 threads
            const int kk = tid & 31, k = kbase + kk;
            const int jb = (tid >> 5) * 8;
            float a0=0,a1=0,a2=0,a3=0,a4=0,a5=0,a6=0,a7=0;
            for (int m = 0; m < kbase; ++m) {
                float am = Am[k][m];
                a0 = fmaf(am, Wm[jb+0][m], a0); a1 = fmaf(am, Wm[jb+1][m], a1);
                a2 = fmaf(am, Wm[jb+2][m], a2); a3 = fmaf(am, Wm[jb+3][m], a3);
                a4 = fmaf(am, Wm[jb+4][m], a4); a5 = fmaf(am, Wm[jb+5][m], a5);
                a6 = fmaf(am, Wm[jb+6][m], a6); a7 = fmaf(am, Wm[jb+7][m], a7);
            }
            Wm[jb+0][k] -= a0; Wm[jb+1][k] -= a1; Wm[jb+2][k] -= a2; Wm[jb+3][k] -= a3;
            Wm[jb+4][k] -= a4; Wm[jb+5][k] -= a5; Wm[jb+6][k] -= a6; Wm[jb+7][k] -= a7;
        }
        __syncthreads();
        // in-panel triangle: thread j owns row j, no cross-thread deps
        if (tid < 128) {
            const int j = tid;
            for (int kk = 0; kk < 32; ++kk) {
                int k = kbase + kk;
                float num = Wm[j][k];
                for (int m = kbase; m < k; ++m) num = fmaf(-Am[k][m], Wm[j][m], num);
                Wm[j][k] = num / Am[k][k];
            }
        }
        __syncthreads();
    }

    unsigned short* o = woT + (size_t)li * 16384;
    for (int idx = tid; idx < 16384; idx += 512) {
        int a = idx >> 7, b = idx & 127;
        o[idx] = f2bf(Wm[b][a] * sqrtf(Am[a][a]));
    }
}

// ================= one-time weight -> bf16 converts =================
__global__ __launch_bounds__(256) void conv_attw_kernel(const float* __restrict__ w,
                                                        unsigned short* __restrict__ o)
{
    int idx = blockIdx.x * 256 + threadIdx.x;   // 4*16384 = 65536
    if (idx < 65536) o[idx] = f2bf(w[idx]);
}

__global__ __launch_bounds__(256) void conv_fcw_kernel(const float* __restrict__ w,
                                                       unsigned short* __restrict__ o)
{
    int idx = blockIdx.x * 256 + threadIdx.x;   // 256 rows x 512 = 131072
    if (idx >= 131072) return;
    int row = idx >> 9, k = idx & 511;
    o[idx] = (k < 500) ? f2bf(w[row * 500 + k]) : (unsigned short)0;
}

// ================= bf16 MFMA GEMMs =================
// Block: 64 rows x 128 cols, 256 threads = 4 waves, wave w owns rows [16w,16w+16).
// LDS bf16 tiles padded to 136 elems/row. mfma_f32_16x16x32_bf16, C/D: col=l&15,
// row=(l>>4)*4+reg [verified].

// ---- input FC: h0 = relu(x @ w.T + b) -> two buffers; B pre-converted bf16 [128][512] ----
__global__ __launch_bounds__(256) void fc_relu_mfma_kernel(const float* __restrict__ x,
                                                           const unsigned short* __restrict__ wbf,
                                                           const float* __restrict__ b,
                                                           float* __restrict__ h0,
                                                           float* __restrict__ h1,
                                                           int nrows)
{
    __shared__ unsigned short Asm[64 * 136];
    __shared__ unsigned short Bsm[128 * 136];
    const int tid  = threadIdx.x;
    const int n0   = blockIdx.x * 64;
    const int lane = tid & 63;
    const int wv   = tid >> 6;
    const int lrow = lane & 15;
    const int kgrp = lane >> 4;

    f32x4 acc[8];
#pragma unroll
    for (int t = 0; t < 8; ++t) acc[t] = (f32x4){0.f, 0.f, 0.f, 0.f};

    for (int kc = 0; kc < 512; kc += 128) {
        for (int cid = tid; cid < 128 * 16; cid += 256) {
            int r = cid >> 4, c8 = cid & 15;
            *reinterpret_cast<bf16x8*>(&Bsm[r * 136 + c8 * 8]) =
                *reinterpret_cast<const bf16x8*>(&wbf[r * 512 + kc + c8 * 8]);
        }
        for (int cid = tid; cid < 64 * 16; cid += 256) {
            int r = cid >> 4, c8 = cid & 15;
            int n = n0 + r;
            int kg = kc + c8 * 8;
            union { unsigned short u[8]; bf16x8 v; } t;
            if (n < nrows && kg + 8 <= 500) {
                const float* src = &x[(size_t)n * 500 + kg];
                float4 v0 = *reinterpret_cast<const float4*>(src);
                float4 v1 = *reinterpret_cast<const float4*>(src + 4);
                t.u[0]=f2bf(v0.x); t.u[1]=f2bf(v0.y); t.u[2]=f2bf(v0.z); t.u[3]=f2bf(v0.w);
                t.u[4]=f2bf(v1.x); t.u[5]=f2bf(v1.y); t.u[6]=f2bf(v1.z); t.u[7]=f2bf(v1.w);
            } else if (n < nrows) {
#pragma unroll
                for (int e = 0; e < 8; ++e)
                    t.u[e] = (kg + e < 500) ? f2bf(x[(size_t)n * 500 + kg + e]) : (unsigned short)0;
            } else {
#pragma unroll
                for (int e = 0; e < 8; ++e) t.u[e] = 0;
            }
            *reinterpret_cast<bf16x8*>(&Asm[r * 136 + c8 * 8]) = t.v;
        }
        __syncthreads();
#pragma unroll
        for (int kt = 0; kt < 4; ++kt) {
            int koff = kt * 32 + kgrp * 8;
            bf16x8 av = *reinterpret_cast<const bf16x8*>(&Asm[(wv * 16 + lrow) * 136 + koff]);
#pragma unroll
            for (int t = 0; t < 8; ++t) {
                bf16x8 bv = *reinterpret_cast<const bf16x8*>(&Bsm[(t * 16 + lrow) * 136 + koff]);
                acc[t] = __builtin_amdgcn_mfma_f32_16x16x32_bf16(av, bv, acc[t], 0, 0, 0);
            }
        }
        __syncthreads();
    }
#pragma unroll
    for (int t = 0; t < 8; ++t) {
        int j = t * 16 + lrow;
        float bj = b[j];
#pragma unroll
        for (int r = 0; r < 4; ++r) {
            int n = n0 + wv * 16 + kgrp * 4 + r;
            if (n < nrows) {
                float v = fmaxf(acc[t][r] + bj, 0.f);
                h0[(size_t)n * 128 + j] = v;
                h1[(size_t)n * 128 + j] = v;
            }
        }
    }
}

// ---- generic 128x128 GEMM, bf16 MFMA, B pre-converted bf16, f32 epilogue ----
template <int MODE>
__global__ __launch_bounds__(256) void gemm128_mfma_kernel(const float* __restrict__ A0,
                                                           const float* __restrict__ A1,
                                                           const unsigned short* __restrict__ Bw,
                                                           const float* __restrict__ bias,
                                                           const float* __restrict__ watt,
                                                           float* __restrict__ outp,
                                                           float c0, float c1, float theta,
                                                           int nrows)
{
    __shared__ unsigned short Asm[64 * 136];
    __shared__ unsigned short Bsm[128 * 136];
    const int tid  = threadIdx.x;
    const int n0   = blockIdx.x * 64;
    const int lane = tid & 63;
    const int wv   = tid >> 6;
    const int lrow = lane & 15;
    const int kgrp = lane >> 4;

    for (int cid = tid; cid < 128 * 16; cid += 256) {
        int r = cid >> 4, c8 = cid & 15;
        *reinterpret_cast<bf16x8*>(&Bsm[r * 136 + c8 * 8]) =
            *reinterpret_cast<const bf16x8*>(&Bw[r * 128 + c8 * 8]);
    }
    for (int cid = tid; cid < 64 * 16; cid += 256) {
        int r = cid >> 4, c8 = cid & 15;
        int n = n0 + r;
        union { unsigned short u[8]; bf16x8 v; } t;
        if (n < nrows) {
            const float* s0 = &A0[(size_t)n * 128 + c8 * 8];
            float4 a0 = *reinterpret_cast<const float4*>(s0);
            float4 a1 = *reinterpret_cast<const float4*>(s0 + 4);
            if (MODE == 1) {
                const float* s1 = &A1[(size_t)n * 128 + c8 * 8];
                float4 b0 = *reinterpret_cast<const float4*>(s1);
                float4 b1 = *reinterpret_cast<const float4*>(s1 + 4);
                a0.x = c0 * a0.x + c1 * b0.x; a0.y = c0 * a0.y + c1 * b0.y;
                a0.z = c0 * a0.z + c1 * b0.z; a0.w = c0 * a0.w + c1 * b0.w;
                a1.x = c0 * a1.x + c1 * b1.x; a1.y = c0 * a1.y + c1 * b1.y;
                a1.z = c0 * a1.z + c1 * b1.z; a1.w = c0 * a1.w + c1 * b1.w;
            }
            t.u[0]=f2bf(a0.x); t.u[1]=f2bf(a0.y); t.u[2]=f2bf(a0.z); t.u[3]=f2bf(a0.w);
            t.u[4]=f2bf(a1.x); t.u[5]=f2bf(a1.y); t.u[6]=f2bf(a1.z); t.u[7]=f2bf(a1.w);
        } else {
#pragma unroll
            for (int e = 0; e < 8; ++e) t.u[e] = 0;
        }
        *reinterpret_cast<bf16x8*>(&Asm[r * 136 + c8 * 8]) = t.v;
    }
    __syncthreads();

    f32x4 acc[8];
#pragma unroll
    for (int t = 0; t < 8; ++t) acc[t] = (f32x4){0.f, 0.f, 0.f, 0.f};
#pragma unroll
    for (int kt = 0; kt < 4; ++kt) {
        int koff = kt * 32 + kgrp * 8;
        bf16x8 av = *reinterpret_cast<const bf16x8*>(&Asm[(wv * 16 + lrow) * 136 + koff]);
#pragma unroll
        for (int t = 0; t < 8; ++t) {
            bf16x8 bv = *reinterpret_cast<const bf16x8*>(&Bsm[(t * 16 + lrow) * 136 + koff]);
            acc[t] = __builtin_amdgcn_mfma_f32_16x16x32_bf16(av, bv, acc[t], 0, 0, 0);
        }
    }

#pragma unroll
    for (int t = 0; t < 8; ++t) {
        int j = t * 16 + lrow;
#pragma unroll
        for (int r = 0; r < 4; ++r) {
            int n = n0 + wv * 16 + kgrp * 4 + r;
            if (n >= nrows) continue;
            float v = acc[t][r];
            if (MODE == 0) {
                v += bias[j];
            } else {
                float s = c0 * A0[(size_t)n * 128 + j] + c1 * A1[(size_t)n * 128 + j];
                v = theta * v + (1.f - theta) * s;
                v = tanhf(v);
                v = fmaxf(v, 0.f);
                if (watt) v *= watt[(size_t)n * 128 + j];
            }
            outp[(size_t)n * 128 + j] = v;
        }
    }
}

// ---------------- attention elementwise (view 0) — writes hout IN-PLACE over h ----------------
__global__ __launch_bounds__(256) void att_kernel(float* __restrict__ h,
                                                  const float* __restrict__ x2g,
                                                  const float* __restrict__ cw,
                                                  const float* __restrict__ mwp,
                                                  float* __restrict__ watt,
                                                  int nrows)
{
    __shared__ float hrow[2][132];
    __shared__ float orow[2][132];
    __shared__ float red[2][2][2];
    const int tid = threadIdx.x;
    const int c   = tid & 127;
    const int rl  = tid >> 7;
    const int n   = blockIdx.x * 2 + rl;
    const bool valid = n < nrows;
    float hv = 0.f, x2v = 0.f;
    if (valid) { hv = h[(size_t)n * 128 + c]; x2v = x2g[(size_t)n * 128 + c]; }
    hrow[rl][c + 2] = hv;
    if (c < 2) { hrow[rl][c] = 0.f; hrow[rl][c + 130] = 0.f; }
    const float w0 = cw[0], w1 = cw[1], w2 = cw[2], w3 = cw[3], w4 = cw[4];
    __syncthreads();
    float x1 = w0 * hrow[rl][c] + w1 * hrow[rl][c + 1] + w2 * hrow[rl][c + 2]
             + w3 * hrow[rl][c + 3] + w4 * hrow[rl][c + 4];
    float p1 = x1, p2 = x2v;
#pragma unroll
    for (int off = 32; off; off >>= 1) { p1 += __shfl_xor(p1, off); p2 += __shfl_xor(p2, off); }
    int wir = (tid >> 6) & 1;
    if ((tid & 63) == 0) { red[rl][0][wir] = p1; red[rl][1][wir] = p2; }
    __syncthreads();
    float s1 = red[rl][0][0] + red[rl][0][1];
    float s2 = red[rl][1][0] + red[rl][1][1];
    float m  = sigmoidf_(mwp[0]);
    float o  = m * sigmoidf_(s1 * x2v) + (1.f - m) * sigmoidf_(s2 * x1);
    orow[rl][c + 2] = o;
    if (c < 2) { orow[rl][c] = 0.f; orow[rl][c + 130] = 0.f; }
    __syncthreads();
    float wv = w0 * orow[rl][c] + w1 * orow[rl][c + 1] + w2 * orow[rl][c + 2]
             + w3 * orow[rl][c + 3] + w4 * orow[rl][c + 4];
    wv = sigmoidf_(wv);
    if (valid) {
        watt[(size_t)n * 128 + c] = wv;
        h[(size_t)n * 128 + c]    = hv * wv;
    }
}

// ================= CSR build (counting sort by destination row) =================
__global__ __launch_bounds__(256) void hist_kernel(const int* __restrict__ rows,
                                                   int* __restrict__ rcnt)
{
    int gid = blockIdx.x * 256 + threadIdx.x;
    if (gid >= 2 * N_EDGES) return;
    int vsel = (gid >= N_EDGES) ? 1 : 0;
    atomicAdd(&rcnt[vsel * N_NODES + rows[gid]], 1);
}

__global__ __launch_bounds__(1024) void scan_kernel(int* __restrict__ rcnt)
{
    __shared__ int s[2][1024];
    int* c = rcnt + blockIdx.x * N_NODES;
    const int tid = threadIdx.x;
    int running = 0;
    for (int base = 0; base < N_NODES; base += 1024) {
        int idx = base + tid;
        int val = (idx < N_NODES) ? c[idx] : 0;
        int buf = 0;
        s[0][tid] = val;
        __syncthreads();
#pragma unroll
        for (int off = 1; off < 1024; off <<= 1) {
            int t = s[buf][tid];
            if (tid >= off) t += s[buf][tid - off];
            s[buf ^ 1][tid] = t;
            buf ^= 1;
            __syncthreads();
        }
        int excl = s[buf][tid] - val;
        if (idx < N_NODES) c[idx] = running + excl;
        running += s[buf][1023];
        __syncthreads();
    }
}

__global__ __launch_bounds__(256) void scatter_kernel(const int* __restrict__ rows,
                                                      const int* __restrict__ cols,
                                                      const float* __restrict__ vals,
                                                      int* __restrict__ rcnt,
                                                      int* __restrict__ scol,
                                                      float* __restrict__ sval)
{
    int gid = blockIdx.x * 256 + threadIdx.x;
    if (gid >= 2 * N_EDGES) return;
    int vsel = (gid >= N_EDGES) ? 1 : 0;
    int pos = atomicAdd(&rcnt[vsel * N_NODES + rows[gid]], 1);
    scol[vsel * N_EDGES + pos] = cols[gid];
    sval[vsel * N_EDGES + pos] = vals[gid];
}

// ---------------- SpMM gather: one row per 32-lane half-wave, 4 ch/lane ----------------
__global__ __launch_bounds__(256) void spmm_csr_kernel(const int* __restrict__ rend,
                                                       const int* __restrict__ scol,
                                                       const float* __restrict__ sval,
                                                       const float* __restrict__ h,
                                                       float* __restrict__ hi)
{
    const int tid  = threadIdx.x;
    const int row  = blockIdx.x * 8 + (tid >> 5);
    if (row >= N_NODES) return;
    const int lane = tid & 31;
    const int c0   = lane * 4;
    const int beg  = (row == 0) ? 0 : rend[row - 1];
    const int end  = rend[row];
    float4 acc = {0.f, 0.f, 0.f, 0.f};
    for (int e = beg; e < end; ++e) {
        int   c = scol[e];
        float v = sval[e];
        const float4 hv = *reinterpret_cast<const float4*>(&h[(size_t)c * 128 + c0]);
        acc.x += v * hv.x; acc.y += v * hv.y; acc.z += v * hv.z; acc.w += v * hv.w;
    }
    *reinterpret_cast<float4*>(&hi[(size_t)row * 128 + c0]) = acc;
}

// ---------------- final: logits (both views), 4x log-softmax outputs ----------------
__global__ __launch_bounds__(256) void out_kernel(const float* __restrict__ hA,
                                                  const float* __restrict__ hB,
                                                  const float* __restrict__ ow,
                                                  const float* __restrict__ ob,
                                                  float* __restrict__ outp,
                                                  int nrows)
{
    const int tid  = threadIdx.x;
    const int lane = tid & 63;
    const int wid  = tid >> 6;
    const int n    = blockIdx.x * 4 + wid;
    if (n >= nrows) return;
    const int j   = lane & 15;
    const int seg = lane >> 4;
    const float* a  = &hA[(size_t)n * 128 + seg * 32];
    const float* bx = &hB[(size_t)n * 128 + seg * 32];
    const float* wj = &ow[j * 128 + seg * 32];
    float d0 = 0.f, d1 = 0.f;
#pragma unroll
    for (int k = 0; k < 32; ++k) { float wv = wj[k]; d0 += a[k] * wv; d1 += bx[k] * wv; }
    d0 += __shfl_xor(d0, 16); d0 += __shfl_xor(d0, 32);
    d1 += __shfl_xor(d1, 16); d1 += __shfl_xor(d1, 32);
    float bias = ob[j];
    float l0 = d0 + bias, l1 = d1 + bias, lt = l0 + l1;

    float mt = lt, m0 = l0, m1 = l1;
#pragma unroll
    for (int off = 8; off; off >>= 1) {
        mt = fmaxf(mt, __shfl_xor(mt, off));
        m0 = fmaxf(m0, __shfl_xor(m0, off));
        m1 = fmaxf(m1, __shfl_xor(m1, off));
    }
    float et = __expf(lt - mt), e0 = __expf(l0 - m0), e1 = __expf(l1 - m1);
    float st = et, s0 = e0, s1 = e1;
#pragma unroll
    for (int off = 8; off; off >>= 1) {
        st += __shfl_xor(st, off);
        s0 += __shfl_xor(s0, off);
        s1 += __shfl_xor(s1, off);
    }
    float ot  = lt - mt - __logf(st);
    float o0  = l0 - m0 - __logf(s0);
    float o1  = l1 - m1 - __logf(s1);
    if (lane < 16) {
        size_t base = (size_t)n * 16 + j;
        outp[0 * 800000 + base] = ot;
        outp[1 * 800000 + base] = 0.5f * (o0 + o1);
        outp[2 * 800000 + base] = o0;
        outp[3 * 800000 + base] = o1;
    }
}

// ---------------- host launcher ----------------
extern "C" void kernel_launch(void* const* d_in, const int* in_sizes, int n_in,
                              void* d_out, int out_size, void* d_ws, size_t ws_size,
                              hipStream_t stream)
{
    const float* x          = (const float*)d_in[0];
    const int*   rows       = (const int*)d_in[1];
    const int*   cols       = (const int*)d_in[2];
    const float* vals       = (const float*)d_in[3];
    const float* fc_w       = (const float*)d_in[4];
    const float* fc_b       = (const float*)d_in[5];
    const float* conv_w     = (const float*)d_in[6];
    const float* att_conv_w = (const float*)d_in[7];
    const float* att_fc_w   = (const float*)d_in[8];
    const float* att_fc_b   = (const float*)d_in[9];
    const float* att_mix_w  = (const float*)d_in[10];
    const float* out_w      = (const float*)d_in[11];
    const float* out_b      = (const float*)d_in[12];
    float* outp = (float*)d_out;

    // ws (floats): 6*SB (153.6MB) + WoT_bf 32K + attw_bf 32K + fcw_bf 64K + Am_g 64K
    //              + CSR 13.2MB  ≈ 167.6MB  (< proven 179.5MB)
    const size_t SB = (size_t)N_NODES * 128;
    float* ws     = (float*)d_ws;
    float* B_h0a  = ws + 0 * SB;
    float* B_h0b  = ws + 1 * SB;
    float* B_hA   = ws + 2 * SB;   // h (view0); gated in-place by att_kernel
    float* B_hB   = ws + 3 * SB;   // h (view1)
    float* B_hi   = ws + 4 * SB;   // x2 scratch + spmm output
    float* B_watt = ws + 5 * SB;
    float* extra  = ws + 6 * SB;
    unsigned short* WoT_bf  = (unsigned short*)extra;                 // 4*16384 bf16
    unsigned short* attw_bf = (unsigned short*)(extra + 32768);       // 4*16384 bf16
    unsigned short* fcw_bf  = (unsigned short*)(extra + 65536);       // 2*128*512 bf16
    float*          Am_g    = extra + 131072;                         // 4*16384 f32
    float* csr0   = extra + 196608;
    int*   rcnt   = (int*)csr0;                       // [2][N_NODES]
    int*   scol   = (int*)(csr0 + 2 * N_NODES);       // [2][N_EDGES]
    float* sval   = csr0 + 2 * N_NODES + 2 * N_EDGES; // [2][N_EDGES]

    static const float thetas[4] = {0.40546511f, 0.22314355f, 0.15415068f, 0.11778304f};

    // ---- CSR build (both views) ----
    hipMemsetAsync(rcnt, 0, 2 * N_NODES * sizeof(int), stream);
    hist_kernel<<<6250, 256, 0, stream>>>(rows, rcnt);
    scan_kernel<<<2, 1024, 0, stream>>>(rcnt);
    scatter_kernel<<<6250, 256, 0, stream>>>(rows, cols, vals, rcnt, scol, sval);

    // ---- ortho: parallel WtW, then 4-block LDL^T+solve (writes bf16 WoT) ----
    wtw_kernel<<<256, 256, 0, stream>>>(conv_w, Am_g);
    conv_attw_kernel<<<256, 256, 0, stream>>>(att_fc_w, attw_bf);
    conv_fcw_kernel<<<512, 256, 0, stream>>>(fc_w, fcw_bf);
    chol_solve_kernel<<<4, 512, 0, stream>>>(Am_g, conv_w, WoT_bf);

    // input FC for both views (bf16 MFMA, pre-converted weights)
    fc_relu_mfma_kernel<<<782, 256, 0, stream>>>(x, fcw_bf, fc_b, B_h0a, B_hA, N_NODES);
    fc_relu_mfma_kernel<<<782, 256, 0, stream>>>(x + (size_t)N_NODES * F_IN,
                                                 fcw_bf + 128 * 512, fc_b + 128,
                                                 B_h0b, B_hB, N_NODES);

    for (int i = 0; i < 4; ++i) {
        // ---- view 0: attention (x2 into B_hi, then gate B_hA in-place) ----
        gemm128_mfma_kernel<0><<<782, 256, 0, stream>>>(B_hA, nullptr,
                                                        attw_bf + (size_t)i * 16384,
                                                        att_fc_b + i * 128, nullptr,
                                                        B_hi, 1.f, 0.f, 0.f, N_NODES);
        att_kernel<<<25000, 256, 0, stream>>>(B_hA, B_hi, att_conv_w + i * 5,
                                              att_mix_w + i, B_watt, N_NODES);
        // ---- view 0: GCN layer ----
        spmm_csr_kernel<<<6250, 256, 0, stream>>>(rcnt, scol, sval, B_hA, B_hi);
        gemm128_mfma_kernel<1><<<782, 256, 0, stream>>>(B_hi, B_h0a, WoT_bf + (size_t)i * 16384,
                                                        nullptr, nullptr, B_hA,
                                                        0.9f, 0.1f, thetas[i], N_NODES);
        // ---- view 1: GCN layer (then * w_att) ----
        spmm_csr_kernel<<<6250, 256, 0, stream>>>(rcnt + N_NODES, scol + N_EDGES,
                                                  sval + N_EDGES, B_hB, B_hi);
        gemm128_mfma_kernel<1><<<782, 256, 0, stream>>>(B_hi, B_h0b, WoT_bf + (size_t)i * 16384,
                                                        nullptr, B_watt, B_hB,
                                                        0.9f, 0.1f, thetas[i], N_NODES);
    }

    out_kernel<<<12500, 256, 0, stream>>>(B_hA, B_hB, out_w, out_b, outp, N_NODES);
}

// Round 10
// 1659.830 us; speedup vs baseline: 8.1297x; 1.1937x over previous
//
#include <hip/hip_runtime.h>
#include <hip/hip_bf16.h>
#include <math.h>

// ---------------- problem constants ----------------
static const int N_NODES = 50000;
static const int N_EDGES = 800000;
static const int F_IN    = 500;
static const int C_DIM   = 128;

using bf16x8 = __attribute__((ext_vector_type(8))) short;   // 8 bf16 in 4 VGPRs
using f32x4  = __attribute__((ext_vector_type(4))) float;   // MFMA accumulator

__device__ __forceinline__ float sigmoidf_(float x) { return 1.f / (1.f + __expf(-x)); }

__device__ __forceinline__ unsigned short f2bf(float f) {
    __hip_bfloat16 h = __float2bfloat16(f);
    unsigned short u;
    __builtin_memcpy(&u, &h, 2);
    return u;
}
__device__ __forceinline__ float bflo(unsigned int w) {   // bf16 in low 16 bits
    unsigned int u = w << 16; float f; __builtin_memcpy(&f, &u, 4); return f;
}
__device__ __forceinline__ float bfhi(unsigned int w) {   // bf16 in high 16 bits
    unsigned int u = w & 0xffff0000u; float f; __builtin_memcpy(&f, &u, 4); return f;
}

// ================= ortho phase 1: A = W^T W + 1e-4 I (full-chip parallel) =================
__global__ __launch_bounds__(256) void wtw_kernel(const float* __restrict__ conv_w,
                                                  float* __restrict__ Am_g)
{
    __shared__ float Wi[128][16];
    __shared__ float Wj[128][16];
    const int bid = blockIdx.x;
    const int li  = bid >> 6;
    const int t6  = bid & 63;
    const int ti  = (t6 >> 3) << 4;
    const int tj  = (t6 & 7) << 4;
    const int tid = threadIdx.x;
    const float* W = conv_w + (size_t)li * 16384;
    for (int idx = tid; idx < 2048; idx += 256) {
        int k = idx >> 4, c = idx & 15;
        Wi[k][c] = W[k * 128 + ti + c];
        Wj[k][c] = W[k * 128 + tj + c];
    }
    __syncthreads();
    const int i = tid >> 4, j = tid & 15;
    float acc = 0.f;
    for (int k = 0; k < 128; ++k) acc = fmaf(Wi[k][i], Wj[k][j], acc);
    if (ti + i == tj + j) acc += 1e-4f;
    Am_g[(size_t)li * 16384 + (ti + i) * 128 + tj + j] = acc;
}

// ================= ortho phase 2: blocked LDL^T (panel=32) + panel-blocked solve =================
// Raw-column LDL^T: Am keeps unscaled columns, D on diagonal. Final matrix identical to the
// per-pivot version (round-8, verified). Solve phase copied verbatim from round 8 (verified).
__global__ __launch_bounds__(512) void chol_solve_kernel(const float* __restrict__ Am_g,
                                                         const float* __restrict__ conv_w,
                                                         unsigned short* __restrict__ woT)
{
    __shared__ float Am[128][129];
    __shared__ float Wm[128][129];
    __shared__ float rkv[32];
    const int li  = blockIdx.x;
    const int tid = threadIdx.x;
    const float* Ag = Am_g  + (size_t)li * 16384;
    const float* Wg = conv_w + (size_t)li * 16384;
    for (int idx = tid; idx < 16384; idx += 512) {
        Am[idx >> 7][idx & 127] = Ag[idx];
        Wm[idx >> 7][idx & 127] = Wg[idx];
    }
    __syncthreads();

    for (int p = 0; p < 4; ++p) {
        const int kb = p * 32;
        // (a) factor 32x32 diagonal block (tiny masked sweeps, lower triangle only)
        for (int kk = 0; kk < 31; ++kk) {
            const int k  = kb + kk;
            const float rk = 1.f / Am[k][k];
            const int R  = 31 - kk;                    // rows k+1 .. kb+31
            for (int idx = tid; idx < R * 32; idx += 512) {
                int i = k + 1 + (idx >> 5);
                int j = kb + (idx & 31);
                if (j > k && j <= i)
                    Am[i][j] = fmaf(-Am[i][k] * rk, Am[j][k], Am[i][j]);
            }
            __syncthreads();
        }
        if (tid < 32) rkv[tid] = 1.f / Am[kb + tid][kb + tid];
        __syncthreads();

        if (p < 3) {
            const int tb = kb + 32;
            const int TR = 128 - tb;
            // (b) finalize panel columns for trailing rows (thread-per-row serial triangle)
            if (tid < TR) {
                const int i = tb + tid;
                for (int kk = 0; kk < 31; ++kk) {
                    const int k = kb + kk;
                    const float f = Am[i][k] * rkv[kk];
                    for (int j = k + 1; j < kb + 32; ++j)
                        Am[i][j] = fmaf(-f, Am[j][k], Am[i][j]);
                }
            }
            __syncthreads();
            // (c) trailing rank-32 update, dense 4x4 register tiles, one barrier
            const int nt = TR >> 2;
            for (int t = tid; t < nt * nt; t += 512) {
                const int ti = t / nt, tj = t - ti * nt;
                if (ti < tj) continue;
                const int i0 = tb + ti * 4, j0 = tb + tj * 4;
                float acc[4][4] = {};
                for (int kk = 0; kk < 32; ++kk) {
                    const int k = kb + kk;
                    const float rk = rkv[kk];
                    float ai[4], aj[4];
#pragma unroll
                    for (int r = 0; r < 4; ++r) ai[r] = Am[i0 + r][k];
#pragma unroll
                    for (int c = 0; c < 4; ++c) aj[c] = Am[j0 + c][k] * rk;
#pragma unroll
                    for (int r = 0; r < 4; ++r)
#pragma unroll
                        for (int c = 0; c < 4; ++c)
                            acc[r][c] = fmaf(ai[r], aj[c], acc[r][c]);
                }
#pragma unroll
                for (int r = 0; r < 4; ++r)
#pragma unroll
                    for (int c = 0; c < 4; ++c)
                        Am[i0 + r][j0 + c] -= acc[r][c];
            }
            __syncthreads();
        }
    }

    // panel-blocked forward solve (z-form), verbatim from round 8 (verified)
    for (int p = 0; p < 4; ++p) {
        const int kbase = p * 32;
        if (p > 0) {
            const int kk = tid & 31, k = kbase + kk;
            const int jb = (tid >> 5) * 8;
            float a0=0,a1=0,a2=0,a3=0,a4=0,a5=0,a6=0,a7=0;
            for (int m = 0; m < kbase; ++m) {
                float am = Am[k][m];
                a0 = fmaf(am, Wm[jb+0][m], a0); a1 = fmaf(am, Wm[jb+1][m], a1);
                a2 = fmaf(am, Wm[jb+2][m], a2); a3 = fmaf(am, Wm[jb+3][m], a3);
                a4 = fmaf(am, Wm[jb+4][m], a4); a5 = fmaf(am, Wm[jb+5][m], a5);
                a6 = fmaf(am, Wm[jb+6][m], a6); a7 = fmaf(am, Wm[jb+7][m], a7);
            }
            Wm[jb+0][k] -= a0; Wm[jb+1][k] -= a1; Wm[jb+2][k] -= a2; Wm[jb+3][k] -= a3;
            Wm[jb+4][k] -= a4; Wm[jb+5][k] -= a5; Wm[jb+6][k] -= a6; Wm[jb+7][k] -= a7;
        }
        __syncthreads();
        if (tid < 128) {
            const int j = tid;
            for (int kk = 0; kk < 32; ++kk) {
                int k = kbase + kk;
                float num = Wm[j][k];
                for (int m = kbase; m < k; ++m) num = fmaf(-Am[k][m], Wm[j][m], num);
                Wm[j][k] = num / Am[k][k];
            }
        }
        __syncthreads();
    }

    unsigned short* o = woT + (size_t)li * 16384;
    for (int idx = tid; idx < 16384; idx += 512) {
        int a = idx >> 7, b = idx & 127;
        o[idx] = f2bf(Wm[b][a] * sqrtf(Am[a][a]));
    }
}

// ================= one-time weight -> bf16 converts =================
__global__ __launch_bounds__(256) void conv_attw_kernel(const float* __restrict__ w,
                                                        unsigned short* __restrict__ o)
{
    int idx = blockIdx.x * 256 + threadIdx.x;
    if (idx < 65536) o[idx] = f2bf(w[idx]);
}

__global__ __launch_bounds__(256) void conv_fcw_kernel(const float* __restrict__ w,
                                                       unsigned short* __restrict__ o)
{
    int idx = blockIdx.x * 256 + threadIdx.x;
    if (idx >= 131072) return;
    int row = idx >> 9, k = idx & 511;
    o[idx] = (k < 500) ? f2bf(w[row * 500 + k]) : (unsigned short)0;
}

// ================= bf16 MFMA GEMMs =================
// Block: 64 rows x 128 cols, 256 threads = 4 waves. LDS padded to 136 elems/row.
// mfma_f32_16x16x32_bf16; C/D: col=l&15, row=(l>>4)*4+reg [verified].

// ---- input FC: relu(x @ w.T + b) -> h0 (bf16), h1 (f32), optional h1 bf16 copy ----
__global__ __launch_bounds__(256) void fc_relu_mfma_kernel(const float* __restrict__ x,
                                                           const unsigned short* __restrict__ wbf,
                                                           const float* __restrict__ b,
                                                           unsigned short* __restrict__ h0bf,
                                                           float* __restrict__ h1,
                                                           unsigned short* __restrict__ h1bf,
                                                           int nrows)
{
    __shared__ unsigned short Asm[64 * 136];
    __shared__ unsigned short Bsm[128 * 136];
    const int tid  = threadIdx.x;
    const int n0   = blockIdx.x * 64;
    const int lane = tid & 63;
    const int wv   = tid >> 6;
    const int lrow = lane & 15;
    const int kgrp = lane >> 4;

    f32x4 acc[8];
#pragma unroll
    for (int t = 0; t < 8; ++t) acc[t] = (f32x4){0.f, 0.f, 0.f, 0.f};

    for (int kc = 0; kc < 512; kc += 128) {
        for (int cid = tid; cid < 128 * 16; cid += 256) {
            int r = cid >> 4, c8 = cid & 15;
            *reinterpret_cast<bf16x8*>(&Bsm[r * 136 + c8 * 8]) =
                *reinterpret_cast<const bf16x8*>(&wbf[r * 512 + kc + c8 * 8]);
        }
        for (int cid = tid; cid < 64 * 16; cid += 256) {
            int r = cid >> 4, c8 = cid & 15;
            int n = n0 + r;
            int kg = kc + c8 * 8;
            union { unsigned short u[8]; bf16x8 v; } t;
            if (n < nrows && kg + 8 <= 500) {
                const float* src = &x[(size_t)n * 500 + kg];
                float4 v0 = *reinterpret_cast<const float4*>(src);
                float4 v1 = *reinterpret_cast<const float4*>(src + 4);
                t.u[0]=f2bf(v0.x); t.u[1]=f2bf(v0.y); t.u[2]=f2bf(v0.z); t.u[3]=f2bf(v0.w);
                t.u[4]=f2bf(v1.x); t.u[5]=f2bf(v1.y); t.u[6]=f2bf(v1.z); t.u[7]=f2bf(v1.w);
            } else if (n < nrows) {
#pragma unroll
                for (int e = 0; e < 8; ++e)
                    t.u[e] = (kg + e < 500) ? f2bf(x[(size_t)n * 500 + kg + e]) : (unsigned short)0;
            } else {
#pragma unroll
                for (int e = 0; e < 8; ++e) t.u[e] = 0;
            }
            *reinterpret_cast<bf16x8*>(&Asm[r * 136 + c8 * 8]) = t.v;
        }
        __syncthreads();
#pragma unroll
        for (int kt = 0; kt < 4; ++kt) {
            int koff = kt * 32 + kgrp * 8;
            bf16x8 av = *reinterpret_cast<const bf16x8*>(&Asm[(wv * 16 + lrow) * 136 + koff]);
#pragma unroll
            for (int t = 0; t < 8; ++t) {
                bf16x8 bv = *reinterpret_cast<const bf16x8*>(&Bsm[(t * 16 + lrow) * 136 + koff]);
                acc[t] = __builtin_amdgcn_mfma_f32_16x16x32_bf16(av, bv, acc[t], 0, 0, 0);
            }
        }
        __syncthreads();
    }
#pragma unroll
    for (int t = 0; t < 8; ++t) {
        int j = t * 16 + lrow;
        float bj = b[j];
#pragma unroll
        for (int r = 0; r < 4; ++r) {
            int n = n0 + wv * 16 + kgrp * 4 + r;
            if (n < nrows) {
                float v = fmaxf(acc[t][r] + bj, 0.f);
                unsigned short vb = f2bf(v);
                h0bf[(size_t)n * 128 + j] = vb;
                h1[(size_t)n * 128 + j]  = v;
                if (h1bf) h1bf[(size_t)n * 128 + j] = vb;
            }
        }
    }
}

// ---- 128x128 GEMM, bf16 MFMA ----
// MODE 0: A from f32 global (x2 = h @ attW^T + bias), out f32.
// MODE 1: A = support (bf16, pre-mixed by spmm); out = relu(tanh(theta*acc + (1-theta)*support))
//         [* watt_bf]; support read back from Asm (LDS); optional bf16 out copy.
template <int MODE>
__global__ __launch_bounds__(256) void gemm128_mfma_kernel(const float* __restrict__ A0f,
                                                           const unsigned short* __restrict__ Abf,
                                                           const unsigned short* __restrict__ Bw,
                                                           const float* __restrict__ bias,
                                                           const unsigned short* __restrict__ wattbf,
                                                           float* __restrict__ outp,
                                                           unsigned short* __restrict__ outbf,
                                                           float theta, int nrows)
{
    __shared__ unsigned short Asm[64 * 136];
    __shared__ unsigned short Bsm[128 * 136];
    const int tid  = threadIdx.x;
    const int n0   = blockIdx.x * 64;
    const int lane = tid & 63;
    const int wv   = tid >> 6;
    const int lrow = lane & 15;
    const int kgrp = lane >> 4;

    for (int cid = tid; cid < 128 * 16; cid += 256) {
        int r = cid >> 4, c8 = cid & 15;
        *reinterpret_cast<bf16x8*>(&Bsm[r * 136 + c8 * 8]) =
            *reinterpret_cast<const bf16x8*>(&Bw[r * 128 + c8 * 8]);
    }
    for (int cid = tid; cid < 64 * 16; cid += 256) {
        int r = cid >> 4, c8 = cid & 15;
        int n = n0 + r;
        if (MODE == 1) {
            bf16x8 v = {};
            if (n < nrows)
                v = *reinterpret_cast<const bf16x8*>(&Abf[(size_t)n * 128 + c8 * 8]);
            *reinterpret_cast<bf16x8*>(&Asm[r * 136 + c8 * 8]) = v;
        } else {
            union { unsigned short u[8]; bf16x8 v; } t;
            if (n < nrows) {
                const float* s0 = &A0f[(size_t)n * 128 + c8 * 8];
                float4 a0 = *reinterpret_cast<const float4*>(s0);
                float4 a1 = *reinterpret_cast<const float4*>(s0 + 4);
                t.u[0]=f2bf(a0.x); t.u[1]=f2bf(a0.y); t.u[2]=f2bf(a0.z); t.u[3]=f2bf(a0.w);
                t.u[4]=f2bf(a1.x); t.u[5]=f2bf(a1.y); t.u[6]=f2bf(a1.z); t.u[7]=f2bf(a1.w);
            } else {
#pragma unroll
                for (int e = 0; e < 8; ++e) t.u[e] = 0;
            }
            *reinterpret_cast<bf16x8*>(&Asm[r * 136 + c8 * 8]) = t.v;
        }
    }
    __syncthreads();

    f32x4 acc[8];
#pragma unroll
    for (int t = 0; t < 8; ++t) acc[t] = (f32x4){0.f, 0.f, 0.f, 0.f};
#pragma unroll
    for (int kt = 0; kt < 4; ++kt) {
        int koff = kt * 32 + kgrp * 8;
        bf16x8 av = *reinterpret_cast<const bf16x8*>(&Asm[(wv * 16 + lrow) * 136 + koff]);
#pragma unroll
        for (int t = 0; t < 8; ++t) {
            bf16x8 bv = *reinterpret_cast<const bf16x8*>(&Bsm[(t * 16 + lrow) * 136 + koff]);
            acc[t] = __builtin_amdgcn_mfma_f32_16x16x32_bf16(av, bv, acc[t], 0, 0, 0);
        }
    }

#pragma unroll
    for (int t = 0; t < 8; ++t) {
        int j = t * 16 + lrow;
#pragma unroll
        for (int r = 0; r < 4; ++r) {
            int rt = wv * 16 + kgrp * 4 + r;     // row within tile
            int n  = n0 + rt;
            if (n >= nrows) continue;
            float v = acc[t][r];
            if (MODE == 0) {
                v += bias[j];
            } else {
                float s = bflo((unsigned int)Asm[rt * 136 + j]);   // support from LDS
                v = theta * v + (1.f - theta) * s;
                v = tanhf(v);
                v = fmaxf(v, 0.f);
                if (wattbf) v *= bflo((unsigned int)wattbf[(size_t)n * 128 + j]);
            }
            outp[(size_t)n * 128 + j] = v;
            if (MODE == 1 && outbf) outbf[(size_t)n * 128 + j] = f2bf(v);
        }
    }
}

// ---------------- attention elementwise (view 0) — gates h in place, emits bf16 shadows ----------------
__global__ __launch_bounds__(256) void att_kernel(float* __restrict__ h,
                                                  const float* __restrict__ x2g,
                                                  const float* __restrict__ cw,
                                                  const float* __restrict__ mwp,
                                                  unsigned short* __restrict__ wattbf,
                                                  unsigned short* __restrict__ hbf,
                                                  int nrows)
{
    __shared__ float hrow[2][132];
    __shared__ float orow[2][132];
    __shared__ float red[2][2][2];
    const int tid = threadIdx.x;
    const int c   = tid & 127;
    const int rl  = tid >> 7;
    const int n   = blockIdx.x * 2 + rl;
    const bool valid = n < nrows;
    float hv = 0.f, x2v = 0.f;
    if (valid) { hv = h[(size_t)n * 128 + c]; x2v = x2g[(size_t)n * 128 + c]; }
    hrow[rl][c + 2] = hv;
    if (c < 2) { hrow[rl][c] = 0.f; hrow[rl][c + 130] = 0.f; }
    const float w0 = cw[0], w1 = cw[1], w2 = cw[2], w3 = cw[3], w4 = cw[4];
    __syncthreads();
    float x1 = w0 * hrow[rl][c] + w1 * hrow[rl][c + 1] + w2 * hrow[rl][c + 2]
             + w3 * hrow[rl][c + 3] + w4 * hrow[rl][c + 4];
    float p1 = x1, p2 = x2v;
#pragma unroll
    for (int off = 32; off; off >>= 1) { p1 += __shfl_xor(p1, off); p2 += __shfl_xor(p2, off); }
    int wir = (tid >> 6) & 1;
    if ((tid & 63) == 0) { red[rl][0][wir] = p1; red[rl][1][wir] = p2; }
    __syncthreads();
    float s1 = red[rl][0][0] + red[rl][0][1];
    float s2 = red[rl][1][0] + red[rl][1][1];
    float m  = sigmoidf_(mwp[0]);
    float o  = m * sigmoidf_(s1 * x2v) + (1.f - m) * sigmoidf_(s2 * x1);
    orow[rl][c + 2] = o;
    if (c < 2) { orow[rl][c] = 0.f; orow[rl][c + 130] = 0.f; }
    __syncthreads();
    float wv = w0 * orow[rl][c] + w1 * orow[rl][c + 1] + w2 * orow[rl][c + 2]
             + w3 * orow[rl][c + 3] + w4 * orow[rl][c + 4];
    wv = sigmoidf_(wv);
    if (valid) {
        float g = hv * wv;
        wattbf[(size_t)n * 128 + c] = f2bf(wv);
        h[(size_t)n * 128 + c]      = g;
        hbf[(size_t)n * 128 + c]    = f2bf(g);
    }
}

// ================= CSR build (counting sort by destination row) =================
__global__ __launch_bounds__(256) void hist_kernel(const int* __restrict__ rows,
                                                   int* __restrict__ rcnt)
{
    int gid = blockIdx.x * 256 + threadIdx.x;
    if (gid >= 2 * N_EDGES) return;
    int vsel = (gid >= N_EDGES) ? 1 : 0;
    atomicAdd(&rcnt[vsel * N_NODES + rows[gid]], 1);
}

__global__ __launch_bounds__(1024) void scan_kernel(int* __restrict__ rcnt)
{
    __shared__ int s[2][1024];
    int* c = rcnt + blockIdx.x * N_NODES;
    const int tid = threadIdx.x;
    int running = 0;
    for (int base = 0; base < N_NODES; base += 1024) {
        int idx = base + tid;
        int val = (idx < N_NODES) ? c[idx] : 0;
        int buf = 0;
        s[0][tid] = val;
        __syncthreads();
#pragma unroll
        for (int off = 1; off < 1024; off <<= 1) {
            int t = s[buf][tid];
            if (tid >= off) t += s[buf][tid - off];
            s[buf ^ 1][tid] = t;
            buf ^= 1;
            __syncthreads();
        }
        int excl = s[buf][tid] - val;
        if (idx < N_NODES) c[idx] = running + excl;
        running += s[buf][1023];
        __syncthreads();
    }
}

__global__ __launch_bounds__(256) void scatter_kernel(const int* __restrict__ rows,
                                                      const int* __restrict__ cols,
                                                      const float* __restrict__ vals,
                                                      int* __restrict__ rcnt,
                                                      int* __restrict__ scol,
                                                      float* __restrict__ sval)
{
    int gid = blockIdx.x * 256 + threadIdx.x;
    if (gid >= 2 * N_EDGES) return;
    int vsel = (gid >= N_EDGES) ? 1 : 0;
    int pos = atomicAdd(&rcnt[vsel * N_NODES + rows[gid]], 1);
    scol[vsel * N_EDGES + pos] = cols[gid];
    sval[vsel * N_EDGES + pos] = vals[gid];
}

// ---------------- SpMM gather (bf16) + fused support mix, bf16 out ----------------
// support[row] = 0.9 * sum_e v_e * h[col_e] + 0.1 * h0[row]
__global__ __launch_bounds__(256) void spmm_csr_kernel(const int* __restrict__ rend,
                                                       const int* __restrict__ scol,
                                                       const float* __restrict__ sval,
                                                       const unsigned short* __restrict__ hbf,
                                                       const unsigned short* __restrict__ h0bf,
                                                       unsigned short* __restrict__ suppbf)
{
    const int tid  = threadIdx.x;
    const int row  = blockIdx.x * 8 + (tid >> 5);
    if (row >= N_NODES) return;
    const int lane = tid & 31;
    const int c0   = lane * 4;
    const int beg  = (row == 0) ? 0 : rend[row - 1];
    const int end  = rend[row];
    float a0 = 0.f, a1 = 0.f, a2 = 0.f, a3 = 0.f;
    for (int e = beg; e < end; ++e) {
        int   c = scol[e];
        float v = sval[e];
        uint2 hv = *reinterpret_cast<const uint2*>(&hbf[(size_t)c * 128 + c0]);
        a0 = fmaf(v, bflo(hv.x), a0);
        a1 = fmaf(v, bfhi(hv.x), a1);
        a2 = fmaf(v, bflo(hv.y), a2);
        a3 = fmaf(v, bfhi(hv.y), a3);
    }
    uint2 h0v = *reinterpret_cast<const uint2*>(&h0bf[(size_t)row * 128 + c0]);
    float s0 = 0.9f * a0 + 0.1f * bflo(h0v.x);
    float s1 = 0.9f * a1 + 0.1f * bfhi(h0v.x);
    float s2 = 0.9f * a2 + 0.1f * bflo(h0v.y);
    float s3 = 0.9f * a3 + 0.1f * bfhi(h0v.y);
    uint2 o;
    o.x = (unsigned int)f2bf(s0) | ((unsigned int)f2bf(s1) << 16);
    o.y = (unsigned int)f2bf(s2) | ((unsigned int)f2bf(s3) << 16);
    *reinterpret_cast<uint2*>(&suppbf[(size_t)row * 128 + c0]) = o;
}

// ---------------- final: logits (both views), 4x log-softmax outputs ----------------
__global__ __launch_bounds__(256) void out_kernel(const float* __restrict__ hA,
                                                  const float* __restrict__ hB,
                                                  const float* __restrict__ ow,
                                                  const float* __restrict__ ob,
                                                  float* __restrict__ outp,
                                                  int nrows)
{
    const int tid  = threadIdx.x;
    const int lane = tid & 63;
    const int wid  = tid >> 6;
    const int n    = blockIdx.x * 4 + wid;
    if (n >= nrows) return;
    const int j   = lane & 15;
    const int seg = lane >> 4;
    const float* a  = &hA[(size_t)n * 128 + seg * 32];
    const float* bx = &hB[(size_t)n * 128 + seg * 32];
    const float* wj = &ow[j * 128 + seg * 32];
    float d0 = 0.f, d1 = 0.f;
#pragma unroll
    for (int k = 0; k < 32; ++k) { float wv = wj[k]; d0 += a[k] * wv; d1 += bx[k] * wv; }
    d0 += __shfl_xor(d0, 16); d0 += __shfl_xor(d0, 32);
    d1 += __shfl_xor(d1, 16); d1 += __shfl_xor(d1, 32);
    float bias = ob[j];
    float l0 = d0 + bias, l1 = d1 + bias, lt = l0 + l1;

    float mt = lt, m0 = l0, m1 = l1;
#pragma unroll
    for (int off = 8; off; off >>= 1) {
        mt = fmaxf(mt, __shfl_xor(mt, off));
        m0 = fmaxf(m0, __shfl_xor(m0, off));
        m1 = fmaxf(m1, __shfl_xor(m1, off));
    }
    float et = __expf(lt - mt), e0 = __expf(l0 - m0), e1 = __expf(l1 - m1);
    float st = et, s0 = e0, s1 = e1;
#pragma unroll
    for (int off = 8; off; off >>= 1) {
        st += __shfl_xor(st, off);
        s0 += __shfl_xor(s0, off);
        s1 += __shfl_xor(s1, off);
    }
    float ot  = lt - mt - __logf(st);
    float o0  = l0 - m0 - __logf(s0);
    float o1  = l1 - m1 - __logf(s1);
    if (lane < 16) {
        size_t base = (size_t)n * 16 + j;
        outp[0 * 800000 + base] = ot;
        outp[1 * 800000 + base] = 0.5f * (o0 + o1);
        outp[2 * 800000 + base] = o0;
        outp[3 * 800000 + base] = o1;
    }
}

// ---------------- host launcher ----------------
extern "C" void kernel_launch(void* const* d_in, const int* in_sizes, int n_in,
                              void* d_out, int out_size, void* d_ws, size_t ws_size,
                              hipStream_t stream)
{
    const float* x          = (const float*)d_in[0];
    const int*   rows       = (const int*)d_in[1];
    const int*   cols       = (const int*)d_in[2];
    const float* vals       = (const float*)d_in[3];
    const float* fc_w       = (const float*)d_in[4];
    const float* fc_b       = (const float*)d_in[5];
    const float* conv_w     = (const float*)d_in[6];
    const float* att_conv_w = (const float*)d_in[7];
    const float* att_fc_w   = (const float*)d_in[8];
    const float* att_fc_b   = (const float*)d_in[9];
    const float* att_mix_w  = (const float*)d_in[10];
    const float* out_w      = (const float*)d_in[11];
    const float* out_b      = (const float*)d_in[12];
    float* outp = (float*)d_out;

    // ws budget: 3 x f32 node-bufs (76.8MB) + 6 x bf16 node-bufs (76.8MB)
    //            + small weights (~0.77MB) + CSR (13.2MB) ≈ 167.6MB (< proven 179.5MB)
    const size_t SBf = (size_t)N_NODES * 128;           // elems per node buffer
    char* base = (char*)d_ws;
    float*          B_hA    = (float*)base;                         base += SBf * 4;
    float*          B_hB    = (float*)base;                         base += SBf * 4;
    float*          B_hi    = (float*)base;                         base += SBf * 4;  // x2 scratch
    unsigned short* h0a_bf  = (unsigned short*)base;                base += SBf * 2;
    unsigned short* h0b_bf  = (unsigned short*)base;                base += SBf * 2;
    unsigned short* hA_bf   = (unsigned short*)base;                base += SBf * 2;
    unsigned short* hB_bf   = (unsigned short*)base;                base += SBf * 2;
    unsigned short* watt_bf = (unsigned short*)base;                base += SBf * 2;
    unsigned short* supp_bf = (unsigned short*)base;                base += SBf * 2;
    unsigned short* WoT_bf  = (unsigned short*)base;                base += 4 * 16384 * 2;
    unsigned short* attw_bf = (unsigned short*)base;                base += 4 * 16384 * 2;
    unsigned short* fcw_bf  = (unsigned short*)base;                base += 2 * 128 * 512 * 2;
    float*          Am_g    = (float*)base;                         base += 4 * 16384 * 4;
    int*            rcnt    = (int*)base;                           base += 2 * N_NODES * 4;
    int*            scol    = (int*)base;                           base += 2 * N_EDGES * 4;
    float*          sval    = (float*)base;

    static const float thetas[4] = {0.40546511f, 0.22314355f, 0.15415068f, 0.11778304f};

    // ---- CSR build (both views) ----
    hipMemsetAsync(rcnt, 0, 2 * N_NODES * sizeof(int), stream);
    hist_kernel<<<6250, 256, 0, stream>>>(rows, rcnt);
    scan_kernel<<<2, 1024, 0, stream>>>(rcnt);
    scatter_kernel<<<6250, 256, 0, stream>>>(rows, cols, vals, rcnt, scol, sval);

    // ---- ortho: parallel WtW, then 4-block blocked LDL^T + solve (writes bf16 WoT) ----
    wtw_kernel<<<256, 256, 0, stream>>>(conv_w, Am_g);
    conv_attw_kernel<<<256, 256, 0, stream>>>(att_fc_w, attw_bf);
    conv_fcw_kernel<<<512, 256, 0, stream>>>(fc_w, fcw_bf);
    chol_solve_kernel<<<4, 512, 0, stream>>>(Am_g, conv_w, WoT_bf);

    // ---- input FC for both views ----
    fc_relu_mfma_kernel<<<782, 256, 0, stream>>>(x, fcw_bf, fc_b,
                                                 h0a_bf, B_hA, (unsigned short*)nullptr, N_NODES);
    fc_relu_mfma_kernel<<<782, 256, 0, stream>>>(x + (size_t)N_NODES * F_IN,
                                                 fcw_bf + 128 * 512, fc_b + 128,
                                                 h0b_bf, B_hB, hB_bf, N_NODES);

    for (int i = 0; i < 4; ++i) {
        // ---- view 0: attention (x2 into B_hi, gate B_hA in place, emit bf16 shadows) ----
        gemm128_mfma_kernel<0><<<782, 256, 0, stream>>>(B_hA, nullptr,
                                                        attw_bf + (size_t)i * 16384,
                                                        att_fc_b + i * 128, nullptr,
                                                        B_hi, nullptr, 0.f, N_NODES);
        att_kernel<<<25000, 256, 0, stream>>>(B_hA, B_hi, att_conv_w + i * 5,
                                              att_mix_w + i, watt_bf, hA_bf, N_NODES);
        // ---- view 0: GCN layer (spmm emits pre-mixed bf16 support) ----
        spmm_csr_kernel<<<6250, 256, 0, stream>>>(rcnt, scol, sval, hA_bf, h0a_bf, supp_bf);
        gemm128_mfma_kernel<1><<<782, 256, 0, stream>>>(nullptr, supp_bf,
                                                        WoT_bf + (size_t)i * 16384,
                                                        nullptr, nullptr,
                                                        B_hA, nullptr, thetas[i], N_NODES);
        // ---- view 1: GCN layer (then * w_att), emits bf16 h for next spmm ----
        spmm_csr_kernel<<<6250, 256, 0, stream>>>(rcnt + N_NODES, scol + N_EDGES,
                                                  sval + N_EDGES, hB_bf, h0b_bf, supp_bf);
        gemm128_mfma_kernel<1><<<782, 256, 0, stream>>>(nullptr, supp_bf,
                                                        WoT_bf + (size_t)i * 16384,
                                                        nullptr, watt_bf,
                                                        B_hB, hB_bf, thetas[i], N_NODES);
    }

    out_kernel<<<12500, 256, 0, stream>>>(B_hA, B_hB, out_w, out_b, outp, N_NODES);
}